// Round 15
// baseline (419.869 us; speedup 1.0000x reference)
//
#include <hip/hip_runtime.h>
#include <hip/hip_bf16.h>
#include <math.h>
#include <stdint.h>

// ---------------------------------------------------------------------------
// Full U-Mamba block. R24: InstanceNorm stats fused into conv epilogue.
//   inorm_stats_k re-read 33.5MB per conv just to make 128 (mu,rsigma);
//   conv blocks hold those outputs in registers. Epilogue: 16-lane shfl
//   butterfly per quad-group -> smem (free after K-loop) -> 4-wave combine
//   -> 128 distinct-address atomicAdds/block into (sum,sumsq) buffers.
//   Apply kernels derive mu/rs from sums (f32-acc stats, more accurate than
//   bf16-y stats). Removes 2 launches + 67MB reads. Two stats buffers
//   (zeroed in setup) avoid re-zero races.
// Kept: R17/R18 HW transcendentals, R20-R22 fused 3-axis dbcscan, R23 bf16
// glue + short8 vectorization.
// ---------------------------------------------------------------------------

typedef __attribute__((ext_vector_type(8))) short short8;   // 8 bf16 = 4 VGPR
typedef __attribute__((ext_vector_type(4))) float f32x4;

__device__ __forceinline__ float siluf(float x){ return x * (1.0f / (1.0f + __expf(-x))); }
__device__ __forceinline__ float softplusf(float x){ return fmaxf(x, 0.0f) + log1pf(__expf(-fabsf(x))); }
// HW-transcendental softplus: v_exp_f32 + v_log_f32 (both ~1ulp), ~6 VALU ops.
__device__ __forceinline__ float softplus_hw(float x){
  float t = __builtin_amdgcn_exp2f(-fabsf(x) * 1.44269504088896f);
  return fmaxf(x, 0.0f) + 0.69314718055995f * __builtin_amdgcn_logf(1.0f + t);
}
__device__ __forceinline__ float b2f(short s){
  unsigned int u = ((unsigned int)(unsigned short)s) << 16;
  float f; __builtin_memcpy(&f, &u, 4); return f;
}
__device__ __forceinline__ short f2b(float v){
  __hip_bfloat16 h = __float2bfloat16(v);
  unsigned short u; __builtin_memcpy(&u, &h, 2); return (short)u;
}

// async global->LDS, 16B per lane; LDS dest is wave-uniform base + lane*16.
__device__ __forceinline__ void gld_lds16(const void* g, void* l){
  __builtin_amdgcn_global_load_lds(
      (__attribute__((address_space(1))) void*)(uintptr_t)g,
      (__attribute__((address_space(3))) void*)(uint32_t)(uintptr_t)l,
      16, 0, 0);
}

// ---------------------------------------------------------------------------
// One-shot setup: zero xpad | zero stats1/2 | pack conv weights a/b -> bf16 |
// mamba weight bf16 tables | negA2[s] = -softplus(A_log[s]) * log2(e).
// ---------------------------------------------------------------------------
__global__ __launch_bounds__(256) void setup_k(uint4* __restrict__ xz,
    const float* __restrict__ cr1w, const float* __restrict__ cr2w,
    const float* __restrict__ lw, const float* __restrict__ rwt,
    const float* __restrict__ dwt, const float* __restrict__ bw,
    const float* __restrict__ cwp, const float* __restrict__ owt,
    const float* __restrict__ alog,
    __hip_bfloat16* __restrict__ W4a, __hip_bfloat16* __restrict__ W4b,
    __hip_bfloat16* __restrict__ Wlr, __hip_bfloat16* __restrict__ Wd,
    __hip_bfloat16* __restrict__ oWp, float* __restrict__ negA2,
    uint4* __restrict__ statz)
{
  int i = blockIdx.x * 256 + threadIdx.x;
  if (i < 628864){ uint4 z; z.x = z.y = z.z = z.w = 0u; xz[i] = z; return; }
  i -= 628864;
  if (i < 110592){
    int tap = i >> 12, co = (i >> 6) & 63, ci = i & 63;
    W4a[i] = __float2bfloat16(cr1w[(co * 64 + ci) * 27 + tap]); return;
  }
  i -= 110592;
  if (i < 110592){
    int tap = i >> 12, co = (i >> 6) & 63, ci = i & 63;
    W4b[i] = __float2bfloat16(cr2w[(co * 64 + ci) * 27 + tap]); return;
  }
  i -= 110592;
  if (i < 16384){
    int row = i >> 6, c = i & 63;
    float v = (row < 128) ? lw[row * 64 + c] : rwt[(row - 128) * 64 + c];
    Wlr[i] = __float2bfloat16(v); return;
  }
  i -= 16384;
  if (i < 20480){
    int row = i >> 7, k = i & 127;
    float v = (row < 128) ? dwt[row * 128 + k]
            : (row < 144 ? bw[(row - 128) * 128 + k] : cwp[(row - 144) * 128 + k]);
    Wd[i] = __float2bfloat16(v); return;
  }
  i -= 20480;
  if (i < 8192){ oWp[i] = __float2bfloat16(owt[i]); return; }
  i -= 8192;
  if (i < 16){ negA2[i] = -softplusf(alog[i]) * 1.44269504088896f; return; }
  i -= 16;
  if (i < 128){ uint4 z; z.x = z.y = z.z = z.w = 0u; statz[i] = z; return; }
}

// ---------------------------------------------------------------------------
// Pack fp32 NCDHW -> padded channels-last bf16 [b][h+1][w+1][d+1][c] (conv1).
// ---------------------------------------------------------------------------
__global__ __launch_bounds__(256) void pack_k(const float* __restrict__ xin,
                                              __hip_bfloat16* __restrict__ xpad)
{
  __shared__ float lds[64 * 33];
  const int t = threadIdx.x, blk = blockIdx.x;
  const int b = blk >> 10, h = (blk >> 5) & 31, w = blk & 31;
  const size_t rbase = ((size_t)(b * 64) << 15) + h * 1024 + w * 32;
  #pragma unroll
  for (int r = 0; r < 8; r++){
    int c = r * 8 + (t >> 5), d = t & 31;
    lds[c * 33 + d] = xin[rbase + (size_t)c * 32768 + d];
  }
  __syncthreads();
  const size_t wbase = (size_t)b * 2515456 + (size_t)(h + 1) * 73984 + (w + 1) * 2176 + 64;
  #pragma unroll
  for (int r = 0; r < 8; r++){
    int d = r * 4 + (t >> 6), c = t & 63;
    xpad[wbase + d * 64 + c] = __float2bfloat16(lds[c * 33 + d]);
  }
}

// ---------------------------------------------------------------------------
// Conv3d implicit GEMM, bf16 MFMA 16x16x32, LDS-staged (m97 pattern, R8).
// R24: epilogue also accumulates per-channel (sum, sumsq) partials into
// stats via butterfly + smem combine + 128 distinct-address atomicAdds.
// ---------------------------------------------------------------------------
__global__ __launch_bounds__(256) void conv_mfma_k(const __hip_bfloat16* __restrict__ xpad,
    const __hip_bfloat16* __restrict__ W4, __hip_bfloat16* __restrict__ y,
    float* __restrict__ stats)
{
  __shared__ short smem[6144];   // [0,4096): B tile; [4096,6144): A tile

  const int t = threadIdx.x;
  const int wave = t >> 6, lane = t & 63;
  const int quad = lane >> 4, ln = lane & 15;

  const int blk = blockIdx.x;          // 512 blocks
  const int xcd = blk & 7, j = blk >> 3;
  const int b = j >> 5, jj = j & 31;
  const int h = xcd * 4 + (jj >> 3);
  const int w0 = (jj & 7) * 4;

  const int bcol = (lane >> 2) * 64 + (lane & 3) * 8;
  const __hip_bfloat16* Bg = xpad + (size_t)b * 2515456 + (size_t)h * 73984
                                  + (size_t)(w0 + wave) * 2176 + bcol;
  const __hip_bfloat16* Ag = W4 + wave * 1024 + bcol;
  short* Bl0 = &smem[wave * 1024];
  short* Bl1 = &smem[wave * 1024 + 512];
  short* Al  = &smem[4096 + wave * 512];

  f32x4 acc[2][4];
  #pragma unroll
  for (int jn = 0; jn < 2; jn++)
    #pragma unroll
    for (int m = 0; m < 4; m++) acc[jn][m] = (f32x4){0.f, 0.f, 0.f, 0.f};

  const int aoff = ln * 32 + quad * 8;
  const int boff = (wave * 32 + ln) * 32 + quad * 8;

  for (int s = 0; s < 54; s++){
    const int t1 = s >> 1, ch = s & 1;
    const int ki = t1 / 9, kj = (t1 / 3) % 3, kk = t1 % 3;
    const int tapoff = ki * 73984 + kj * 2176 + kk * 64 + ch * 32;

    __syncthreads();
    gld_lds16(Bg + tapoff,        Bl0);
    gld_lds16(Bg + tapoff + 1024, Bl1);
    gld_lds16(Ag + t1 * 4096 + ch * 32, Al);
    __syncthreads();

    short8 a0 = *(const short8*)&smem[4096 + aoff];
    short8 a1 = *(const short8*)&smem[4096 + 512 + aoff];
    short8 a2 = *(const short8*)&smem[4096 + 1024 + aoff];
    short8 a3 = *(const short8*)&smem[4096 + 1536 + aoff];
    short8 b0 = *(const short8*)&smem[boff];
    short8 b1 = *(const short8*)&smem[boff + 512];

    acc[0][0] = __builtin_amdgcn_mfma_f32_16x16x32_bf16(a0, b0, acc[0][0], 0, 0, 0);
    acc[0][1] = __builtin_amdgcn_mfma_f32_16x16x32_bf16(a1, b0, acc[0][1], 0, 0, 0);
    acc[0][2] = __builtin_amdgcn_mfma_f32_16x16x32_bf16(a2, b0, acc[0][2], 0, 0, 0);
    acc[0][3] = __builtin_amdgcn_mfma_f32_16x16x32_bf16(a3, b0, acc[0][3], 0, 0, 0);
    acc[1][0] = __builtin_amdgcn_mfma_f32_16x16x32_bf16(a0, b1, acc[1][0], 0, 0, 0);
    acc[1][1] = __builtin_amdgcn_mfma_f32_16x16x32_bf16(a1, b1, acc[1][1], 0, 0, 0);
    acc[1][2] = __builtin_amdgcn_mfma_f32_16x16x32_bf16(a2, b1, acc[1][2], 0, 0, 0);
    acc[1][3] = __builtin_amdgcn_mfma_f32_16x16x32_bf16(a3, b1, acc[1][3], 0, 0, 0);
  }

  const size_t sbase = (size_t)h * 1024 + (w0 + wave) * 32 + ln;
  #pragma unroll
  for (int jn = 0; jn < 2; jn++){
    #pragma unroll
    for (int mt = 0; mt < 4; mt++){
      #pragma unroll
      for (int reg = 0; reg < 4; reg++){
        int co = mt * 16 + quad * 4 + reg;
        y[(((size_t)(b * 64 + co)) << 15) + sbase + jn * 16] = __float2bfloat16(acc[jn][mt][reg]);
      }
    }
  }

  // --- fused InstanceNorm partial stats: (sum, sumsq) per channel --------
  __syncthreads();                 // all smem reads done; reuse as float
  float* sred = (float*)smem;      // [wave][quad][mt][reg][2] = 512 floats
  #pragma unroll
  for (int mt = 0; mt < 4; mt++){
    #pragma unroll
    for (int reg = 0; reg < 4; reg++){
      float a0 = acc[0][mt][reg], a1 = acc[1][mt][reg];
      float s = a0 + a1, s2 = a0 * a0 + a1 * a1;
      #pragma unroll
      for (int m = 1; m < 16; m <<= 1){
        s  += __shfl_xor(s, m);
        s2 += __shfl_xor(s2, m);
      }
      if (ln == 0){
        const int idx = (((wave * 4 + quad) * 4 + mt) * 4 + reg) * 2;
        sred[idx] = s; sred[idx + 1] = s2;
      }
    }
  }
  __syncthreads();
  if (t < 128){
    const int k = t & 1, reg = (t >> 1) & 3, mt = (t >> 3) & 3, q = t >> 5;
    float v = 0.f;
    #pragma unroll
    for (int wv = 0; wv < 4; wv++)
      v += sred[(((wv * 4 + q) * 4 + mt) * 4 + reg) * 2 + k];
    const int co = mt * 16 + q * 4 + reg;
    atomicAdd(&stats[k * 128 + b * 64 + co], v);
  }
}

// ---------------------------------------------------------------------------
// Fused: InstanceNorm-apply + LeakyReLU + residual -> x1b (bf16 NCDHW)
// AND bf16 channels-last re-pack into xpad. mu/rs derived from (sum,sumsq).
// ---------------------------------------------------------------------------
__global__ __launch_bounds__(256) void apply_pack_k(const float* __restrict__ xin,
    const __hip_bfloat16* __restrict__ y, const float* __restrict__ stats,
    __hip_bfloat16* __restrict__ x1b, __hip_bfloat16* __restrict__ xpad)
{
  __shared__ float lds[64 * 33];
  const int t = threadIdx.x, blk = blockIdx.x;
  const int b = blk >> 10, h = (blk >> 5) & 31, w = blk & 31;
  const size_t rbase = ((size_t)(b * 64) << 15) + h * 1024 + w * 32;
  const int c = t >> 2, d0 = (t & 3) * 8;
  const float s1v = stats[b * 64 + c], s2v = stats[128 + b * 64 + c];
  const float mu = s1v * (1.0f / 32768.0f);
  const float var = s2v * (1.0f / 32768.0f) - mu * mu;
  const float rs = rsqrtf(fmaxf(var, 0.f) + 1e-5f);
  const size_t idx = rbase + (size_t)c * 32768 + d0;
  short8 yv = *(const short8*)&y[idx];
  float4 xa = *(const float4*)&xin[idx];
  float4 xb = *(const float4*)&xin[idx + 4];
  short8 o;
  #pragma unroll
  for (int jj = 0; jj < 8; jj++){
    float v = (b2f(yv[jj]) - mu) * rs;
    v = (v >= 0.0f) ? v : 0.01f * v;
    v += (jj < 4) ? ((const float*)&xa)[jj] : ((const float*)&xb)[jj - 4];
    o[jj] = f2b(v);
    lds[c * 33 + d0 + jj] = v;
  }
  *(short8*)&x1b[idx] = o;
  __syncthreads();
  const size_t wbase = (size_t)b * 2515456 + (size_t)(h + 1) * 73984 + (w + 1) * 2176 + 64;
  #pragma unroll
  for (int r = 0; r < 8; r++){
    int d = r * 4 + (t >> 6), cc = t & 63;
    xpad[wbase + d * 64 + cc] = __float2bfloat16(lds[cc * 33 + d]);
  }
}

// ---------------------------------------------------------------------------
// Fused: InstanceNorm-apply + LeakyReLU + residual + LayerNorm over C
// -> bf16 channels-last lnx [pos][64]. mu/rs derived from (sum,sumsq).
// ---------------------------------------------------------------------------
__global__ __launch_bounds__(256) void apply_ln_k(const __hip_bfloat16* __restrict__ x1b,
    const __hip_bfloat16* __restrict__ y, const float* __restrict__ stats,
    const float* __restrict__ lnw, const float* __restrict__ lnb,
    __hip_bfloat16* __restrict__ lnx)
{
  __shared__ float lds[64 * 33];
  __shared__ float s_mu[32], s_rs[32];
  const int t = threadIdx.x, blk = blockIdx.x;
  const int b = blk >> 10, h = (blk >> 5) & 31, w = blk & 31;
  const size_t rbase = ((size_t)(b * 64) << 15) + h * 1024 + w * 32;
  const int c = t >> 2, d0 = (t & 3) * 8;
  const float s1v = stats[b * 64 + c], s2v = stats[128 + b * 64 + c];
  const float mu0 = s1v * (1.0f / 32768.0f);
  const float var0 = s2v * (1.0f / 32768.0f) - mu0 * mu0;
  const float rs0 = rsqrtf(fmaxf(var0, 0.f) + 1e-5f);
  const size_t idx = rbase + (size_t)c * 32768 + d0;
  short8 yv = *(const short8*)&y[idx];
  short8 xv = *(const short8*)&x1b[idx];
  #pragma unroll
  for (int jj = 0; jj < 8; jj++){
    float v = (b2f(yv[jj]) - mu0) * rs0;
    v = (v >= 0.0f) ? v : 0.01f * v;
    lds[c * 33 + d0 + jj] = v + b2f(xv[jj]);
  }
  __syncthreads();
  if (t < 32){
    float s = 0.f, s2 = 0.f;
    for (int cc = 0; cc < 64; cc++){ float v = lds[cc * 33 + t]; s += v; s2 += v * v; }
    float mu = s * (1.f / 64.f);
    float var = s2 * (1.f / 64.f) - mu * mu;
    s_mu[t] = mu; s_rs[t] = rsqrtf(var + 1e-5f);
  }
  __syncthreads();
  const int d = t >> 3, c0 = (t & 7) * 8;
  const int pos = b * 32768 + h * 1024 + w * 32 + d;
  const float mu = s_mu[d], rs = s_rs[d];
  short8 o;
  #pragma unroll
  for (int jj = 0; jj < 8; jj++){
    int cc = c0 + jj;
    o[jj] = f2b((lds[cc * 33 + d] - mu) * rs * lnw[cc] + lnb[cc]);
  }
  *(short8*)&lnx[(size_t)pos * 64 + c0] = o;
}

// ---------------------------------------------------------------------------
// GEMM [65536,64] x [64,256] -> Lbuf (cols 0-127 raw) + Gbuf (silu, 128-255).
// ---------------------------------------------------------------------------
__global__ __launch_bounds__(256) void gemm_lr_k(const __hip_bfloat16* __restrict__ lnx,
    const __hip_bfloat16* __restrict__ Wlr, __hip_bfloat16* __restrict__ Lb,
    __hip_bfloat16* __restrict__ Gb)
{
  const int t = threadIdx.x, wave = t >> 6, lane = t & 63, quad = lane >> 4, ln = lane & 15;
  const int pos0 = blockIdx.x * 64 + wave * 16;
  f32x4 acc[16];
  #pragma unroll
  for (int nt = 0; nt < 16; nt++) acc[nt] = (f32x4){0.f, 0.f, 0.f, 0.f};
  #pragma unroll
  for (int ks = 0; ks < 2; ks++){
    short8 a = *(const short8*)&lnx[(size_t)(pos0 + ln) * 64 + ks * 32 + quad * 8];
    #pragma unroll
    for (int nt = 0; nt < 16; nt++){
      short8 bv = *(const short8*)&Wlr[(nt * 16 + ln) * 64 + ks * 32 + quad * 8];
      acc[nt] = __builtin_amdgcn_mfma_f32_16x16x32_bf16(a, bv, acc[nt], 0, 0, 0);
    }
  }
  #pragma unroll
  for (int nt = 0; nt < 16; nt++){
    int col = nt * 16 + ln;
    #pragma unroll
    for (int reg = 0; reg < 4; reg++){
      int pos = pos0 + quad * 4 + reg;
      float v = acc[nt][reg];
      if (col < 128) Lb[(size_t)pos * 128 + col] = __float2bfloat16(v);
      else           Gb[(size_t)pos * 128 + col - 128] = __float2bfloat16(siluf(v));
    }
  }
}

// ---------------------------------------------------------------------------
// FUSED per-axis: conv1d(k=4)+silu -> LDS | GEMM [64,128]x[128,160] -> LDS |
// selective scan + gate + post-LN + wax-weight -> per-axis Y buffer.
// ONE launch covers all 3 axes: axis = blockIdx.x % 3, j = blockIdx.x / 3.
// Gated-y ALIASES the delta array s_d. B/C stored bf16 (R19 numerics).
// LDS 37.5KB -> 4 blocks/CU. dbc/xl never touch HBM; Y stores only (no RMW).
// ---------------------------------------------------------------------------
__global__ __launch_bounds__(256) void dbcscan_k(const __hip_bfloat16* __restrict__ Lb,
    const float* __restrict__ cw, const float* __restrict__ cb,
    const __hip_bfloat16* __restrict__ Wd, const float* __restrict__ db,
    const __hip_bfloat16* __restrict__ Gb, const float* __restrict__ negA2,
    const float* __restrict__ pnw, const float* __restrict__ pnb,
    const float* __restrict__ axw,
    __hip_bfloat16* __restrict__ Y0, __hip_bfloat16* __restrict__ Y1,
    __hip_bfloat16* __restrict__ Y2)
{
  __shared__ short s_xl[64 * 136];           // silu(conv1d) bf16, row = sl*32+l
  __shared__ short s_d[64 * 128];            // delta bf16; REUSED as gated-y
  __shared__ short s_Bh[2][32][16];          // B bf16 (R19 numerics)
  __shared__ short s_Ch[2][32][16];          // C bf16
  __shared__ float s_stat[2][32][2];         // per-l {sum, sumsq}

  const int t = threadIdx.x;
  const int bid = blockIdx.x;
  const int axis = bid % 3;                  // interleave axes across dispatch
  const int j = bid / 3;                     // 0..1023 (seq pair)
  int sigma;
  if (axis == 0)      sigma = 1024;
  else if (axis == 1) sigma = 32;
  else                sigma = 1;
  __hip_bfloat16* Yax = (axis == 0) ? Y0 : (axis == 1) ? Y1 : Y2;

  // bases for this block's two sequences
  int bases[2];
  #pragma unroll
  for (int s = 0; s < 2; s++){
    const int seq = j * 2 + s;
    const int b = seq >> 10, r1 = (seq >> 5) & 31, r0 = seq & 31;
    if (axis == 0)      bases[s] = b * 32768 + r1 * 32 + r0;
    else if (axis == 1) bases[s] = b * 32768 + r1 * 1024 + r0;
    else                bases[s] = b * 32768 + r1 * 1024 + r0 * 32;
  }

  // --- Phase A: conv1d(k=4) + silu -> s_xl --------------------------------
  {
    const int c0 = (t & 15) * 8;
    const int pibase = t >> 4;
    float4 w4[8]; float cbv[8];
    #pragma unroll
    for (int c = 0; c < 8; c++){ w4[c] = *(const float4*)&cw[(c0 + c) * 4]; cbv[c] = cb[c0 + c]; }
    #pragma unroll
    for (int r = 0; r < 4; r++){
      const int row = pibase + r * 16;          // 0..63
      const int sl_ = row >> 5, l = row & 31;
      const int pos = bases[sl_] + l * sigma;
      float acc[8];
      #pragma unroll
      for (int c = 0; c < 8; c++) acc[c] = cbv[c];
      #pragma unroll
      for (int jt = 0; jt < 4; jt++){
        const int off = 3 - jt;
        if (l >= off){
          short8 lv = *(const short8*)&Lb[(size_t)(pos - off * sigma) * 128 + c0];
          #pragma unroll
          for (int c = 0; c < 8; c++){
            float wv = (jt == 0) ? w4[c].x : (jt == 1) ? w4[c].y : (jt == 2) ? w4[c].z : w4[c].w;
            acc[c] += wv * b2f(lv[c]);
          }
        }
      }
      short8 o;
      #pragma unroll
      for (int c = 0; c < 8; c++) o[c] = f2b(siluf(acc[c]));
      *(short8*)&s_xl[row * 136 + c0] = o;
    }
  }
  __syncthreads();

  // --- Phase B: GEMM [64,128] x [128,160]; epilogue -> s_d / s_Bh / s_Ch --
  const int wave = t >> 6, lane = t & 63, quad = lane >> 4, ln = lane & 15;
  {
    const int rowb = (wave * 16 + ln) * 136;
    f32x4 acc2[10];
    #pragma unroll
    for (int nt = 0; nt < 10; nt++) acc2[nt] = (f32x4){0.f, 0.f, 0.f, 0.f};
    #pragma unroll
    for (int ks = 0; ks < 4; ks++){
      short8 a = *(const short8*)&s_xl[rowb + ks * 32 + quad * 8];
      #pragma unroll
      for (int nt = 0; nt < 10; nt++){
        short8 bv = *(const short8*)&Wd[(nt * 16 + ln) * 128 + ks * 32 + quad * 8];
        acc2[nt] = __builtin_amdgcn_mfma_f32_16x16x32_bf16(a, bv, acc2[nt], 0, 0, 0);
      }
    }
    const int row0 = wave * 16 + quad * 4;
    #pragma unroll
    for (int nt = 0; nt < 10; nt++){
      const int col = nt * 16 + ln;
      const bool isd = col < 128;
      const float dbv = isd ? db[col] : 0.f;
      #pragma unroll
      for (int reg = 0; reg < 4; reg++){
        const int row = row0 + reg;
        float v = acc2[nt][reg];
        if (isd){
          v = fminf(fmaxf(softplus_hw(v + dbv), 1e-4f), 10.f);
          s_d[row * 128 + col] = f2b(v);
        } else {
          const int sl_ = row >> 5, l = row & 31, cc = col - 128;
          if (cc < 16) s_Bh[sl_][l][cc] = f2b(v);
          else         s_Ch[sl_][l][cc - 16] = f2b(v);
        }
      }
    }
  }

  // scan setup
  float A2[16], h[16];
  #pragma unroll
  for (int s = 0; s < 16; s++){ A2[s] = negA2[s]; h[s] = 0.f; }
  const int sl = wave >> 1;                  // seq_local 0/1
  const int half = wave & 1;                 // channel half 0/1
  const int ch = half * 64 + lane;
  const int base = bases[sl];
  const size_t sx = (size_t)sigma * 128;
  const __hip_bfloat16* pg = Gb + (size_t)base * 128 + ch;

  __syncthreads();

  // --- Phase C1: serial scan; dt/xt/B/C from LDS; g from global ----------
  unsigned short gu = *(const unsigned short*)pg;
  #pragma unroll
  for (int l = 0; l < 32; l++){
    unsigned short ngu = 0;
    if (l + 1 < 32) ngu = *(const unsigned short*)(pg + sx);
    const int row = sl * 32 + l;
    float dt = b2f(s_d[row * 128 + ch]);
    float xt = b2f(s_xl[row * 136 + ch]);
    float g = b2f((short)gu);
    float dx = dt * xt;
    short8 Bv0 = *(const short8*)&s_Bh[sl][l][0];
    short8 Bv1 = *(const short8*)&s_Bh[sl][l][8];
    short8 Cv0 = *(const short8*)&s_Ch[sl][l][0];
    short8 Cv1 = *(const short8*)&s_Ch[sl][l][8];
    float y = 0.f;
    #pragma unroll
    for (int s = 0; s < 16; s++){
      const float Bf = b2f((s < 8) ? Bv0[s] : Bv1[s - 8]);
      const float Cf = b2f((s < 8) ? Cv0[s] : Cv1[s - 8]);
      h[s] = __builtin_amdgcn_exp2f(dt * A2[s]) * h[s] + dx * Bf;
      y += h[s] * Cf;
    }
    s_d[row * 128 + ch] = f2b(y * g);        // alias write (gated y)
    gu = ngu;
    pg += sx;
  }
  __syncthreads();

  // --- Phase C2: cooperative per-l reduction (sum, sumsq over 128 ch) ----
  {
    const int row = t >> 2, part = t & 3;    // row = sl2*32 + l2
    const int sl2 = row >> 5, l2 = row & 31;
    const short* yr = &s_d[row * 128 + part * 32];
    float s1 = 0.f, s2 = 0.f;
    #pragma unroll
    for (int i = 0; i < 32; i++){
      float v = b2f(yr[i]);
      s1 += v; s2 += v * v;
    }
    s1 += __shfl_xor(s1, 1); s2 += __shfl_xor(s2, 1);
    s1 += __shfl_xor(s1, 2); s2 += __shfl_xor(s2, 2);
    if (part == 0){ s_stat[sl2][l2][0] = s1; s_stat[sl2][l2][1] = s2; }
  }
  __syncthreads();

  // --- Phase C3: LN over 128 ch + wax -> per-axis Y (store, no RMW) ------
  float a0 = axw[0], a1 = axw[1], a2 = axw[2];
  float mxw = fmaxf(a0, fmaxf(a1, a2));
  float e0 = __expf(a0 - mxw), e1 = __expf(a1 - mxw), e2 = __expf(a2 - mxw);
  float wax = ((axis == 0) ? e0 : (axis == 1) ? e1 : e2) / (e0 + e1 + e2);
  const float pw = pnw[ch], pb = pnb[ch];

  __hip_bfloat16* py = Yax + (size_t)base * 128 + ch;
  #pragma unroll
  for (int l = 0; l < 32; l++){
    float ss1 = s_stat[sl][l][0];
    float ss2 = s_stat[sl][l][1];
    float mu = ss1 * (1.f / 128.f);
    float var = ss2 * (1.f / 128.f) - mu * mu;
    float rs = rsqrtf(fmaxf(var, 0.f) + 1e-5f);
    float yv = b2f(s_d[(sl * 32 + l) * 128 + ch]);
    float o = ((yv - mu) * rs * pw + pb) * wax;
    *(unsigned short*)py = (unsigned short)f2b(o);
    py += sx;
  }
}

// ---------------------------------------------------------------------------
// SINGLE out-projection GEMM over Y0+Y1+Y2 (MFMA is linear in B: three
// accumulating MFMAs sum the axes exactly) + residual finalize.
// ---------------------------------------------------------------------------
__global__ __launch_bounds__(256) void gemm_out_k(const __hip_bfloat16* __restrict__ Y0,
    const __hip_bfloat16* __restrict__ Y1, const __hip_bfloat16* __restrict__ Y2,
    const __hip_bfloat16* __restrict__ oW, const float* __restrict__ xres,
    const float* __restrict__ rsc, float* __restrict__ outp)
{
  const int t = threadIdx.x, wave = t >> 6, lane = t & 63, quad = lane >> 4, ln = lane & 15;
  const int pos0 = blockIdx.x * 64 + wave * 16;
  f32x4 acc[4];
  #pragma unroll
  for (int mt = 0; mt < 4; mt++) acc[mt] = (f32x4){0.f, 0.f, 0.f, 0.f};
  #pragma unroll
  for (int ks = 0; ks < 4; ks++){
    const size_t boffs = (size_t)(pos0 + ln) * 128 + ks * 32 + quad * 8;
    short8 bv0 = *(const short8*)&Y0[boffs];
    short8 bv1 = *(const short8*)&Y1[boffs];
    short8 bv2 = *(const short8*)&Y2[boffs];
    #pragma unroll
    for (int mt = 0; mt < 4; mt++){
      short8 a = *(const short8*)&oW[(mt * 16 + ln) * 128 + ks * 32 + quad * 8];
      acc[mt] = __builtin_amdgcn_mfma_f32_16x16x32_bf16(a, bv0, acc[mt], 0, 0, 0);
      acc[mt] = __builtin_amdgcn_mfma_f32_16x16x32_bf16(a, bv1, acc[mt], 0, 0, 0);
      acc[mt] = __builtin_amdgcn_mfma_f32_16x16x32_bf16(a, bv2, acc[mt], 0, 0, 0);
    }
  }
  float rs = rsc[0];
  const int pos = pos0 + ln;
  const int bb = pos >> 15, hwd = pos & 32767;
  #pragma unroll
  for (int mt = 0; mt < 4; mt++){
    #pragma unroll
    for (int reg = 0; reg < 4; reg++){
      int co = mt * 16 + quad * 4 + reg;
      size_t idx = (((size_t)(bb * 64 + co)) << 15) + hwd;
      outp[idx] = xres[idx] + rs * acc[mt][reg];
    }
  }
}

// ---------------------------------------------------------------------------
extern "C" void kernel_launch(void* const* d_in, const int* in_sizes, int n_in,
                              void* d_out, int out_size, void* d_ws, size_t ws_size,
                              hipStream_t stream)
{
  const float* x      = (const float*)d_in[0];
  const float* cr1w   = (const float*)d_in[1];
  const float* cr2w   = (const float*)d_in[3];
  const float* ln_w   = (const float*)d_in[5];
  const float* ln_b   = (const float*)d_in[6];
  const float* left_w = (const float*)d_in[7];
  const float* c1dw   = (const float*)d_in[8];
  const float* c1db   = (const float*)d_in[9];
  const float* dw     = (const float*)d_in[10];
  const float* db     = (const float*)d_in[11];
  const float* bpw    = (const float*)d_in[12];
  const float* cpw    = (const float*)d_in[13];
  const float* alog   = (const float*)d_in[14];
  const float* rw     = (const float*)d_in[15];
  const float* pnw    = (const float*)d_in[16];
  const float* pnb    = (const float*)d_in[17];
  const float* ow     = (const float*)d_in[18];
  const float* rsc    = (const float*)d_in[19];
  const float* axw    = (const float*)d_in[20];
  float* out = (float*)d_out;                       // final out; ybuf alias pre-gemm_out
  float* wsf = (float*)d_ws;

  __hip_bfloat16* ybuf = (__hip_bfloat16*)d_out;               // conv out bf16 (33.5MB < 67MB)
  __hip_bfloat16* x1b  = (__hip_bfloat16*)wsf;                 // x1 bf16 (dead after apply_ln -> Y0)
  float* stats1 = wsf + 4194304;                               // 256 f (sum | sumsq)
  float* stats2 = wsf + 4194560;                               // 256 f
  float* negA2  = wsf + 4194816;                               // 16 f
  __hip_bfloat16* W4a  = (__hip_bfloat16*)(wsf + 4195072);     // 110,592 bf16
  __hip_bfloat16* W4b  = W4a + 110592;                         // ends f-off 4,305,664
  __hip_bfloat16* Wlr  = (__hip_bfloat16*)(wsf + 4305664);     // 16,384 bf16
  __hip_bfloat16* Wdbc = (__hip_bfloat16*)(wsf + 4313856);     // 20,480 bf16
  __hip_bfloat16* oWp  = (__hip_bfloat16*)(wsf + 4324096);     // 8,192 bf16
  __hip_bfloat16* xpad = (__hip_bfloat16*)(wsf + 4328192);     // 5,030,912 bf16
  __hip_bfloat16* lnx  = xpad;                                 // alias (post-conv)
  __hip_bfloat16* Lbuf = (__hip_bfloat16*)(wsf + 6843648);     // 8,388,608 bf16
  __hip_bfloat16* Gbuf = (__hip_bfloat16*)(wsf + 11037952);    // 8,388,608 bf16
  __hip_bfloat16* Y0   = (__hip_bfloat16*)wsf;                 // (x1b region, post-apply_ln)
  __hip_bfloat16* Y1   = (__hip_bfloat16*)(wsf + 15232256);    // 8,388,608 bf16
  __hip_bfloat16* Y2   = (__hip_bfloat16*)(wsf + 19426560);    // 8,388,608 bf16

  setup_k<<<3498, 256, 0, stream>>>((uint4*)xpad, cr1w, cr2w, left_w, rw, dw, bpw, cpw, ow,
                                    alog, W4a, W4b, Wlr, Wdbc, oWp, negA2,
                                    (uint4*)stats1);

  // conv-res block 1 (stats fused into conv epilogue)
  pack_k<<<2048, 256, 0, stream>>>(x, xpad);
  conv_mfma_k<<<512, 256, 0, stream>>>(xpad, W4a, ybuf, stats1);
  apply_pack_k<<<2048, 256, 0, stream>>>(x, ybuf, stats1, x1b, xpad);
  // conv-res block 2 (fused apply + LayerNorm; x2 never materialized)
  conv_mfma_k<<<512, 256, 0, stream>>>(xpad, W4b, ybuf, stats2);
  apply_ln_k<<<2048, 256, 0, stream>>>(x1b, ybuf, stats2, ln_w, ln_b, lnx);

  // mamba: axis-independent projection once
  gemm_lr_k<<<1024, 256, 0, stream>>>(lnx, Wlr, Lbuf, Gbuf);

  // ALL 3 axes in one launch (axis = bid%3); per-axis Y buffers, no RMW
  dbcscan_k<<<3072, 256, 0, stream>>>(Lbuf, c1dw, c1db, Wdbc, db, Gbuf, negA2,
                                      pnw, pnb, axw, Y0, Y1, Y2);

  // single out-projection over Y0+Y1+Y2 + residual finalize
  gemm_out_k<<<1024, 256, 0, stream>>>(Y0, Y1, Y2, oWp, x, rsc, out);
}

// Round 16
// 409.921 us; speedup vs baseline: 1.0243x; 1.0243x over previous
//
#include <hip/hip_runtime.h>
#include <hip/hip_bf16.h>
#include <math.h>
#include <stdint.h>

// ---------------------------------------------------------------------------
// Full U-Mamba block. R25: conv barrier halving — 2 channel-groups per stage.
//   conv_mfma_k was 54 stages x 2 barriers (each a vmcnt(0) drain) at only
//   2 blocks/CU (grid-capped) -> barrier drain un-hideable. The ci=64 K-dim
//   was artificially split into two 32-wide stages; staging both halves per
//   tap gives 27 stages / 54 barriers, same glds (6/wave/stage), same 432
//   MFMAs. LDS 12.3 -> 24KB (still no occupancy impact).
//   R24 kept (stats fused into conv epilogue): cross-round tail noise is
//   +/-25-45us (R21-R24 tails moved with no code change; clocks differ),
//   R24's structure is byte-accounting-sound and absmax improved.
// Kept: R17/R18 HW transcendentals, R20-R22 fused 3-axis dbcscan, R23 bf16
// glue + short8 vectorization, R24 fused conv stats.
// ---------------------------------------------------------------------------

typedef __attribute__((ext_vector_type(8))) short short8;   // 8 bf16 = 4 VGPR
typedef __attribute__((ext_vector_type(4))) float f32x4;

__device__ __forceinline__ float siluf(float x){ return x * (1.0f / (1.0f + __expf(-x))); }
__device__ __forceinline__ float softplusf(float x){ return fmaxf(x, 0.0f) + log1pf(__expf(-fabsf(x))); }
// HW-transcendental softplus: v_exp_f32 + v_log_f32 (both ~1ulp), ~6 VALU ops.
__device__ __forceinline__ float softplus_hw(float x){
  float t = __builtin_amdgcn_exp2f(-fabsf(x) * 1.44269504088896f);
  return fmaxf(x, 0.0f) + 0.69314718055995f * __builtin_amdgcn_logf(1.0f + t);
}
__device__ __forceinline__ float b2f(short s){
  unsigned int u = ((unsigned int)(unsigned short)s) << 16;
  float f; __builtin_memcpy(&f, &u, 4); return f;
}
__device__ __forceinline__ short f2b(float v){
  __hip_bfloat16 h = __float2bfloat16(v);
  unsigned short u; __builtin_memcpy(&u, &h, 2); return (short)u;
}

// async global->LDS, 16B per lane; LDS dest is wave-uniform base + lane*16.
__device__ __forceinline__ void gld_lds16(const void* g, void* l){
  __builtin_amdgcn_global_load_lds(
      (__attribute__((address_space(1))) void*)(uintptr_t)g,
      (__attribute__((address_space(3))) void*)(uint32_t)(uintptr_t)l,
      16, 0, 0);
}

// ---------------------------------------------------------------------------
// One-shot setup: zero xpad | zero stats1/2 | pack conv weights a/b -> bf16 |
// mamba weight bf16 tables | negA2[s] = -softplus(A_log[s]) * log2(e).
// ---------------------------------------------------------------------------
__global__ __launch_bounds__(256) void setup_k(uint4* __restrict__ xz,
    const float* __restrict__ cr1w, const float* __restrict__ cr2w,
    const float* __restrict__ lw, const float* __restrict__ rwt,
    const float* __restrict__ dwt, const float* __restrict__ bw,
    const float* __restrict__ cwp, const float* __restrict__ owt,
    const float* __restrict__ alog,
    __hip_bfloat16* __restrict__ W4a, __hip_bfloat16* __restrict__ W4b,
    __hip_bfloat16* __restrict__ Wlr, __hip_bfloat16* __restrict__ Wd,
    __hip_bfloat16* __restrict__ oWp, float* __restrict__ negA2,
    uint4* __restrict__ statz)
{
  int i = blockIdx.x * 256 + threadIdx.x;
  if (i < 628864){ uint4 z; z.x = z.y = z.z = z.w = 0u; xz[i] = z; return; }
  i -= 628864;
  if (i < 110592){
    int tap = i >> 12, co = (i >> 6) & 63, ci = i & 63;
    W4a[i] = __float2bfloat16(cr1w[(co * 64 + ci) * 27 + tap]); return;
  }
  i -= 110592;
  if (i < 110592){
    int tap = i >> 12, co = (i >> 6) & 63, ci = i & 63;
    W4b[i] = __float2bfloat16(cr2w[(co * 64 + ci) * 27 + tap]); return;
  }
  i -= 110592;
  if (i < 16384){
    int row = i >> 6, c = i & 63;
    float v = (row < 128) ? lw[row * 64 + c] : rwt[(row - 128) * 64 + c];
    Wlr[i] = __float2bfloat16(v); return;
  }
  i -= 16384;
  if (i < 20480){
    int row = i >> 7, k = i & 127;
    float v = (row < 128) ? dwt[row * 128 + k]
            : (row < 144 ? bw[(row - 128) * 128 + k] : cwp[(row - 144) * 128 + k]);
    Wd[i] = __float2bfloat16(v); return;
  }
  i -= 20480;
  if (i < 8192){ oWp[i] = __float2bfloat16(owt[i]); return; }
  i -= 8192;
  if (i < 16){ negA2[i] = -softplusf(alog[i]) * 1.44269504088896f; return; }
  i -= 16;
  if (i < 128){ uint4 z; z.x = z.y = z.z = z.w = 0u; statz[i] = z; return; }
}

// ---------------------------------------------------------------------------
// Pack fp32 NCDHW -> padded channels-last bf16 [b][h+1][w+1][d+1][c] (conv1).
// ---------------------------------------------------------------------------
__global__ __launch_bounds__(256) void pack_k(const float* __restrict__ xin,
                                              __hip_bfloat16* __restrict__ xpad)
{
  __shared__ float lds[64 * 33];
  const int t = threadIdx.x, blk = blockIdx.x;
  const int b = blk >> 10, h = (blk >> 5) & 31, w = blk & 31;
  const size_t rbase = ((size_t)(b * 64) << 15) + h * 1024 + w * 32;
  #pragma unroll
  for (int r = 0; r < 8; r++){
    int c = r * 8 + (t >> 5), d = t & 31;
    lds[c * 33 + d] = xin[rbase + (size_t)c * 32768 + d];
  }
  __syncthreads();
  const size_t wbase = (size_t)b * 2515456 + (size_t)(h + 1) * 73984 + (w + 1) * 2176 + 64;
  #pragma unroll
  for (int r = 0; r < 8; r++){
    int d = r * 4 + (t >> 6), c = t & 63;
    xpad[wbase + d * 64 + c] = __float2bfloat16(lds[c * 33 + d]);
  }
}

// ---------------------------------------------------------------------------
// Conv3d implicit GEMM, bf16 MFMA 16x16x32, LDS-staged.
// R25: 27 stages (full ci=64 per tap) instead of 54 -> half the barriers.
// Per stage per wave: 4 B-glds (32 d x 64 ci) + 2 A-glds (16 co x 64 ci),
// 16 MFMAs (2 ch-groups x 2 jn x 4 m). Epilogue: bf16 y + fused stats (R24).
// ---------------------------------------------------------------------------
__global__ __launch_bounds__(256) void conv_mfma_k(const __hip_bfloat16* __restrict__ xpad,
    const __hip_bfloat16* __restrict__ W4, __hip_bfloat16* __restrict__ y,
    float* __restrict__ stats)
{
  __shared__ short smem[12288];  // [0,8192): B 4w x (32d x 64ci); [8192,12288): A [ch][wslice]

  const int t = threadIdx.x;
  const int wave = t >> 6, lane = t & 63;
  const int quad = lane >> 4, ln = lane & 15;

  const int blk = blockIdx.x;          // 512 blocks
  const int xcd = blk & 7, j = blk >> 3;
  const int b = j >> 5, jj = j & 31;
  const int h = xcd * 4 + (jj >> 3);
  const int w0 = (jj & 7) * 4;

  const int bcol = (lane >> 2) * 64 + (lane & 3) * 8;
  const __hip_bfloat16* Bg = xpad + (size_t)b * 2515456 + (size_t)h * 73984
                                  + (size_t)(w0 + wave) * 2176 + bcol;
  const __hip_bfloat16* Ag = W4 + wave * 1024 + bcol;
  short* Bl0 = &smem[wave * 2048];          // d 0-15,  ci 0-31
  short* Bl1 = &smem[wave * 2048 + 512];    // d 16-31, ci 0-31
  short* Bl2 = &smem[wave * 2048 + 1024];   // d 0-15,  ci 32-63
  short* Bl3 = &smem[wave * 2048 + 1536];   // d 16-31, ci 32-63
  short* Al0 = &smem[8192 + wave * 512];           // ch0: 16 co x 32 ci
  short* Al1 = &smem[8192 + 2048 + wave * 512];    // ch1

  f32x4 acc[2][4];
  #pragma unroll
  for (int jn = 0; jn < 2; jn++)
    #pragma unroll
    for (int m = 0; m < 4; m++) acc[jn][m] = (f32x4){0.f, 0.f, 0.f, 0.f};

  const int aoff = ln * 32 + quad * 8;
  const int boff = wave * 2048 + ln * 32 + quad * 8;

  for (int t1 = 0; t1 < 27; t1++){
    const int ki = t1 / 9, kj = (t1 / 3) % 3, kk = t1 % 3;
    const int tapoff = ki * 73984 + kj * 2176 + kk * 64;

    __syncthreads();
    gld_lds16(Bg + tapoff,             Bl0);
    gld_lds16(Bg + tapoff + 1024,      Bl1);
    gld_lds16(Bg + tapoff + 32,        Bl2);
    gld_lds16(Bg + tapoff + 1024 + 32, Bl3);
    gld_lds16(Ag + t1 * 4096,          Al0);
    gld_lds16(Ag + t1 * 4096 + 32,     Al1);
    __syncthreads();

    // channel-group 0 (ci 0-31)
    {
      short8 a0 = *(const short8*)&smem[8192 + aoff];
      short8 a1 = *(const short8*)&smem[8192 + 512 + aoff];
      short8 a2 = *(const short8*)&smem[8192 + 1024 + aoff];
      short8 a3 = *(const short8*)&smem[8192 + 1536 + aoff];
      short8 b0 = *(const short8*)&smem[boff];
      short8 b1 = *(const short8*)&smem[boff + 512];
      acc[0][0] = __builtin_amdgcn_mfma_f32_16x16x32_bf16(a0, b0, acc[0][0], 0, 0, 0);
      acc[0][1] = __builtin_amdgcn_mfma_f32_16x16x32_bf16(a1, b0, acc[0][1], 0, 0, 0);
      acc[0][2] = __builtin_amdgcn_mfma_f32_16x16x32_bf16(a2, b0, acc[0][2], 0, 0, 0);
      acc[0][3] = __builtin_amdgcn_mfma_f32_16x16x32_bf16(a3, b0, acc[0][3], 0, 0, 0);
      acc[1][0] = __builtin_amdgcn_mfma_f32_16x16x32_bf16(a0, b1, acc[1][0], 0, 0, 0);
      acc[1][1] = __builtin_amdgcn_mfma_f32_16x16x32_bf16(a1, b1, acc[1][1], 0, 0, 0);
      acc[1][2] = __builtin_amdgcn_mfma_f32_16x16x32_bf16(a2, b1, acc[1][2], 0, 0, 0);
      acc[1][3] = __builtin_amdgcn_mfma_f32_16x16x32_bf16(a3, b1, acc[1][3], 0, 0, 0);
    }
    // channel-group 1 (ci 32-63)
    {
      short8 a0 = *(const short8*)&smem[8192 + 2048 + aoff];
      short8 a1 = *(const short8*)&smem[8192 + 2048 + 512 + aoff];
      short8 a2 = *(const short8*)&smem[8192 + 2048 + 1024 + aoff];
      short8 a3 = *(const short8*)&smem[8192 + 2048 + 1536 + aoff];
      short8 b0 = *(const short8*)&smem[boff + 1024];
      short8 b1 = *(const short8*)&smem[boff + 1536];
      acc[0][0] = __builtin_amdgcn_mfma_f32_16x16x32_bf16(a0, b0, acc[0][0], 0, 0, 0);
      acc[0][1] = __builtin_amdgcn_mfma_f32_16x16x32_bf16(a1, b0, acc[0][1], 0, 0, 0);
      acc[0][2] = __builtin_amdgcn_mfma_f32_16x16x32_bf16(a2, b0, acc[0][2], 0, 0, 0);
      acc[0][3] = __builtin_amdgcn_mfma_f32_16x16x32_bf16(a3, b0, acc[0][3], 0, 0, 0);
      acc[1][0] = __builtin_amdgcn_mfma_f32_16x16x32_bf16(a0, b1, acc[1][0], 0, 0, 0);
      acc[1][1] = __builtin_amdgcn_mfma_f32_16x16x32_bf16(a1, b1, acc[1][1], 0, 0, 0);
      acc[1][2] = __builtin_amdgcn_mfma_f32_16x16x32_bf16(a2, b1, acc[1][2], 0, 0, 0);
      acc[1][3] = __builtin_amdgcn_mfma_f32_16x16x32_bf16(a3, b1, acc[1][3], 0, 0, 0);
    }
  }

  const size_t sbase = (size_t)h * 1024 + (w0 + wave) * 32 + ln;
  #pragma unroll
  for (int jn = 0; jn < 2; jn++){
    #pragma unroll
    for (int mt = 0; mt < 4; mt++){
      #pragma unroll
      for (int reg = 0; reg < 4; reg++){
        int co = mt * 16 + quad * 4 + reg;
        y[(((size_t)(b * 64 + co)) << 15) + sbase + jn * 16] = __float2bfloat16(acc[jn][mt][reg]);
      }
    }
  }

  // --- fused InstanceNorm partial stats: (sum, sumsq) per channel --------
  __syncthreads();                 // all smem reads done; reuse as float
  float* sred = (float*)smem;      // [wave][quad][mt][reg][2] = 512 floats
  #pragma unroll
  for (int mt = 0; mt < 4; mt++){
    #pragma unroll
    for (int reg = 0; reg < 4; reg++){
      float a0 = acc[0][mt][reg], a1 = acc[1][mt][reg];
      float s = a0 + a1, s2 = a0 * a0 + a1 * a1;
      #pragma unroll
      for (int m = 1; m < 16; m <<= 1){
        s  += __shfl_xor(s, m);
        s2 += __shfl_xor(s2, m);
      }
      if (ln == 0){
        const int idx = (((wave * 4 + quad) * 4 + mt) * 4 + reg) * 2;
        sred[idx] = s; sred[idx + 1] = s2;
      }
    }
  }
  __syncthreads();
  if (t < 128){
    const int k = t & 1, reg = (t >> 1) & 3, mt = (t >> 3) & 3, q = t >> 5;
    float v = 0.f;
    #pragma unroll
    for (int wv = 0; wv < 4; wv++)
      v += sred[(((wv * 4 + q) * 4 + mt) * 4 + reg) * 2 + k];
    const int co = mt * 16 + q * 4 + reg;
    atomicAdd(&stats[k * 128 + b * 64 + co], v);
  }
}

// ---------------------------------------------------------------------------
// Fused: InstanceNorm-apply + LeakyReLU + residual -> x1b (bf16 NCDHW)
// AND bf16 channels-last re-pack into xpad. mu/rs derived from (sum,sumsq).
// ---------------------------------------------------------------------------
__global__ __launch_bounds__(256) void apply_pack_k(const float* __restrict__ xin,
    const __hip_bfloat16* __restrict__ y, const float* __restrict__ stats,
    __hip_bfloat16* __restrict__ x1b, __hip_bfloat16* __restrict__ xpad)
{
  __shared__ float lds[64 * 33];
  const int t = threadIdx.x, blk = blockIdx.x;
  const int b = blk >> 10, h = (blk >> 5) & 31, w = blk & 31;
  const size_t rbase = ((size_t)(b * 64) << 15) + h * 1024 + w * 32;
  const int c = t >> 2, d0 = (t & 3) * 8;
  const float s1v = stats[b * 64 + c], s2v = stats[128 + b * 64 + c];
  const float mu = s1v * (1.0f / 32768.0f);
  const float var = s2v * (1.0f / 32768.0f) - mu * mu;
  const float rs = rsqrtf(fmaxf(var, 0.f) + 1e-5f);
  const size_t idx = rbase + (size_t)c * 32768 + d0;
  short8 yv = *(const short8*)&y[idx];
  float4 xa = *(const float4*)&xin[idx];
  float4 xb = *(const float4*)&xin[idx + 4];
  short8 o;
  #pragma unroll
  for (int jj = 0; jj < 8; jj++){
    float v = (b2f(yv[jj]) - mu) * rs;
    v = (v >= 0.0f) ? v : 0.01f * v;
    v += (jj < 4) ? ((const float*)&xa)[jj] : ((const float*)&xb)[jj - 4];
    o[jj] = f2b(v);
    lds[c * 33 + d0 + jj] = v;
  }
  *(short8*)&x1b[idx] = o;
  __syncthreads();
  const size_t wbase = (size_t)b * 2515456 + (size_t)(h + 1) * 73984 + (w + 1) * 2176 + 64;
  #pragma unroll
  for (int r = 0; r < 8; r++){
    int d = r * 4 + (t >> 6), cc = t & 63;
    xpad[wbase + d * 64 + cc] = __float2bfloat16(lds[cc * 33 + d]);
  }
}

// ---------------------------------------------------------------------------
// Fused: InstanceNorm-apply + LeakyReLU + residual + LayerNorm over C
// -> bf16 channels-last lnx [pos][64]. mu/rs derived from (sum,sumsq).
// ---------------------------------------------------------------------------
__global__ __launch_bounds__(256) void apply_ln_k(const __hip_bfloat16* __restrict__ x1b,
    const __hip_bfloat16* __restrict__ y, const float* __restrict__ stats,
    const float* __restrict__ lnw, const float* __restrict__ lnb,
    __hip_bfloat16* __restrict__ lnx)
{
  __shared__ float lds[64 * 33];
  __shared__ float s_mu[32], s_rs[32];
  const int t = threadIdx.x, blk = blockIdx.x;
  const int b = blk >> 10, h = (blk >> 5) & 31, w = blk & 31;
  const size_t rbase = ((size_t)(b * 64) << 15) + h * 1024 + w * 32;
  const int c = t >> 2, d0 = (t & 3) * 8;
  const float s1v = stats[b * 64 + c], s2v = stats[128 + b * 64 + c];
  const float mu0 = s1v * (1.0f / 32768.0f);
  const float var0 = s2v * (1.0f / 32768.0f) - mu0 * mu0;
  const float rs0 = rsqrtf(fmaxf(var0, 0.f) + 1e-5f);
  const size_t idx = rbase + (size_t)c * 32768 + d0;
  short8 yv = *(const short8*)&y[idx];
  short8 xv = *(const short8*)&x1b[idx];
  #pragma unroll
  for (int jj = 0; jj < 8; jj++){
    float v = (b2f(yv[jj]) - mu0) * rs0;
    v = (v >= 0.0f) ? v : 0.01f * v;
    lds[c * 33 + d0 + jj] = v + b2f(xv[jj]);
  }
  __syncthreads();
  if (t < 32){
    float s = 0.f, s2 = 0.f;
    for (int cc = 0; cc < 64; cc++){ float v = lds[cc * 33 + t]; s += v; s2 += v * v; }
    float mu = s * (1.f / 64.f);
    float var = s2 * (1.f / 64.f) - mu * mu;
    s_mu[t] = mu; s_rs[t] = rsqrtf(var + 1e-5f);
  }
  __syncthreads();
  const int d = t >> 3, c0 = (t & 7) * 8;
  const int pos = b * 32768 + h * 1024 + w * 32 + d;
  const float mu = s_mu[d], rs = s_rs[d];
  short8 o;
  #pragma unroll
  for (int jj = 0; jj < 8; jj++){
    int cc = c0 + jj;
    o[jj] = f2b((lds[cc * 33 + d] - mu) * rs * lnw[cc] + lnb[cc]);
  }
  *(short8*)&lnx[(size_t)pos * 64 + c0] = o;
}

// ---------------------------------------------------------------------------
// GEMM [65536,64] x [64,256] -> Lbuf (cols 0-127 raw) + Gbuf (silu, 128-255).
// ---------------------------------------------------------------------------
__global__ __launch_bounds__(256) void gemm_lr_k(const __hip_bfloat16* __restrict__ lnx,
    const __hip_bfloat16* __restrict__ Wlr, __hip_bfloat16* __restrict__ Lb,
    __hip_bfloat16* __restrict__ Gb)
{
  const int t = threadIdx.x, wave = t >> 6, lane = t & 63, quad = lane >> 4, ln = lane & 15;
  const int pos0 = blockIdx.x * 64 + wave * 16;
  f32x4 acc[16];
  #pragma unroll
  for (int nt = 0; nt < 16; nt++) acc[nt] = (f32x4){0.f, 0.f, 0.f, 0.f};
  #pragma unroll
  for (int ks = 0; ks < 2; ks++){
    short8 a = *(const short8*)&lnx[(size_t)(pos0 + ln) * 64 + ks * 32 + quad * 8];
    #pragma unroll
    for (int nt = 0; nt < 16; nt++){
      short8 bv = *(const short8*)&Wlr[(nt * 16 + ln) * 64 + ks * 32 + quad * 8];
      acc[nt] = __builtin_amdgcn_mfma_f32_16x16x32_bf16(a, bv, acc[nt], 0, 0, 0);
    }
  }
  #pragma unroll
  for (int nt = 0; nt < 16; nt++){
    int col = nt * 16 + ln;
    #pragma unroll
    for (int reg = 0; reg < 4; reg++){
      int pos = pos0 + quad * 4 + reg;
      float v = acc[nt][reg];
      if (col < 128) Lb[(size_t)pos * 128 + col] = __float2bfloat16(v);
      else           Gb[(size_t)pos * 128 + col - 128] = __float2bfloat16(siluf(v));
    }
  }
}

// ---------------------------------------------------------------------------
// FUSED per-axis: conv1d(k=4)+silu -> LDS | GEMM [64,128]x[128,160] -> LDS |
// selective scan + gate + post-LN + wax-weight -> per-axis Y buffer.
// ONE launch covers all 3 axes: axis = blockIdx.x % 3, j = blockIdx.x / 3.
// Gated-y ALIASES the delta array s_d. B/C stored bf16 (R19 numerics).
// LDS 37.5KB -> 4 blocks/CU. dbc/xl never touch HBM; Y stores only (no RMW).
// ---------------------------------------------------------------------------
__global__ __launch_bounds__(256) void dbcscan_k(const __hip_bfloat16* __restrict__ Lb,
    const float* __restrict__ cw, const float* __restrict__ cb,
    const __hip_bfloat16* __restrict__ Wd, const float* __restrict__ db,
    const __hip_bfloat16* __restrict__ Gb, const float* __restrict__ negA2,
    const float* __restrict__ pnw, const float* __restrict__ pnb,
    const float* __restrict__ axw,
    __hip_bfloat16* __restrict__ Y0, __hip_bfloat16* __restrict__ Y1,
    __hip_bfloat16* __restrict__ Y2)
{
  __shared__ short s_xl[64 * 136];           // silu(conv1d) bf16, row = sl*32+l
  __shared__ short s_d[64 * 128];            // delta bf16; REUSED as gated-y
  __shared__ short s_Bh[2][32][16];          // B bf16 (R19 numerics)
  __shared__ short s_Ch[2][32][16];          // C bf16
  __shared__ float s_stat[2][32][2];         // per-l {sum, sumsq}

  const int t = threadIdx.x;
  const int bid = blockIdx.x;
  const int axis = bid % 3;                  // interleave axes across dispatch
  const int j = bid / 3;                     // 0..1023 (seq pair)
  int sigma;
  if (axis == 0)      sigma = 1024;
  else if (axis == 1) sigma = 32;
  else                sigma = 1;
  __hip_bfloat16* Yax = (axis == 0) ? Y0 : (axis == 1) ? Y1 : Y2;

  // bases for this block's two sequences
  int bases[2];
  #pragma unroll
  for (int s = 0; s < 2; s++){
    const int seq = j * 2 + s;
    const int b = seq >> 10, r1 = (seq >> 5) & 31, r0 = seq & 31;
    if (axis == 0)      bases[s] = b * 32768 + r1 * 32 + r0;
    else if (axis == 1) bases[s] = b * 32768 + r1 * 1024 + r0;
    else                bases[s] = b * 32768 + r1 * 1024 + r0 * 32;
  }

  // --- Phase A: conv1d(k=4) + silu -> s_xl --------------------------------
  {
    const int c0 = (t & 15) * 8;
    const int pibase = t >> 4;
    float4 w4[8]; float cbv[8];
    #pragma unroll
    for (int c = 0; c < 8; c++){ w4[c] = *(const float4*)&cw[(c0 + c) * 4]; cbv[c] = cb[c0 + c]; }
    #pragma unroll
    for (int r = 0; r < 4; r++){
      const int row = pibase + r * 16;          // 0..63
      const int sl_ = row >> 5, l = row & 31;
      const int pos = bases[sl_] + l * sigma;
      float acc[8];
      #pragma unroll
      for (int c = 0; c < 8; c++) acc[c] = cbv[c];
      #pragma unroll
      for (int jt = 0; jt < 4; jt++){
        const int off = 3 - jt;
        if (l >= off){
          short8 lv = *(const short8*)&Lb[(size_t)(pos - off * sigma) * 128 + c0];
          #pragma unroll
          for (int c = 0; c < 8; c++){
            float wv = (jt == 0) ? w4[c].x : (jt == 1) ? w4[c].y : (jt == 2) ? w4[c].z : w4[c].w;
            acc[c] += wv * b2f(lv[c]);
          }
        }
      }
      short8 o;
      #pragma unroll
      for (int c = 0; c < 8; c++) o[c] = f2b(siluf(acc[c]));
      *(short8*)&s_xl[row * 136 + c0] = o;
    }
  }
  __syncthreads();

  // --- Phase B: GEMM [64,128] x [128,160]; epilogue -> s_d / s_Bh / s_Ch --
  const int wave = t >> 6, lane = t & 63, quad = lane >> 4, ln = lane & 15;
  {
    const int rowb = (wave * 16 + ln) * 136;
    f32x4 acc2[10];
    #pragma unroll
    for (int nt = 0; nt < 10; nt++) acc2[nt] = (f32x4){0.f, 0.f, 0.f, 0.f};
    #pragma unroll
    for (int ks = 0; ks < 4; ks++){
      short8 a = *(const short8*)&s_xl[rowb + ks * 32 + quad * 8];
      #pragma unroll
      for (int nt = 0; nt < 10; nt++){
        short8 bv = *(const short8*)&Wd[(nt * 16 + ln) * 128 + ks * 32 + quad * 8];
        acc2[nt] = __builtin_amdgcn_mfma_f32_16x16x32_bf16(a, bv, acc2[nt], 0, 0, 0);
      }
    }
    const int row0 = wave * 16 + quad * 4;
    #pragma unroll
    for (int nt = 0; nt < 10; nt++){
      const int col = nt * 16 + ln;
      const bool isd = col < 128;
      const float dbv = isd ? db[col] : 0.f;
      #pragma unroll
      for (int reg = 0; reg < 4; reg++){
        const int row = row0 + reg;
        float v = acc2[nt][reg];
        if (isd){
          v = fminf(fmaxf(softplus_hw(v + dbv), 1e-4f), 10.f);
          s_d[row * 128 + col] = f2b(v);
        } else {
          const int sl_ = row >> 5, l = row & 31, cc = col - 128;
          if (cc < 16) s_Bh[sl_][l][cc] = f2b(v);
          else         s_Ch[sl_][l][cc - 16] = f2b(v);
        }
      }
    }
  }

  // scan setup
  float A2[16], h[16];
  #pragma unroll
  for (int s = 0; s < 16; s++){ A2[s] = negA2[s]; h[s] = 0.f; }
  const int sl = wave >> 1;                  // seq_local 0/1
  const int half = wave & 1;                 // channel half 0/1
  const int ch = half * 64 + lane;
  const int base = bases[sl];
  const size_t sx = (size_t)sigma * 128;
  const __hip_bfloat16* pg = Gb + (size_t)base * 128 + ch;

  __syncthreads();

  // --- Phase C1: serial scan; dt/xt/B/C from LDS; g from global ----------
  unsigned short gu = *(const unsigned short*)pg;
  #pragma unroll
  for (int l = 0; l < 32; l++){
    unsigned short ngu = 0;
    if (l + 1 < 32) ngu = *(const unsigned short*)(pg + sx);
    const int row = sl * 32 + l;
    float dt = b2f(s_d[row * 128 + ch]);
    float xt = b2f(s_xl[row * 136 + ch]);
    float g = b2f((short)gu);
    float dx = dt * xt;
    short8 Bv0 = *(const short8*)&s_Bh[sl][l][0];
    short8 Bv1 = *(const short8*)&s_Bh[sl][l][8];
    short8 Cv0 = *(const short8*)&s_Ch[sl][l][0];
    short8 Cv1 = *(const short8*)&s_Ch[sl][l][8];
    float y = 0.f;
    #pragma unroll
    for (int s = 0; s < 16; s++){
      const float Bf = b2f((s < 8) ? Bv0[s] : Bv1[s - 8]);
      const float Cf = b2f((s < 8) ? Cv0[s] : Cv1[s - 8]);
      h[s] = __builtin_amdgcn_exp2f(dt * A2[s]) * h[s] + dx * Bf;
      y += h[s] * Cf;
    }
    s_d[row * 128 + ch] = f2b(y * g);        // alias write (gated y)
    gu = ngu;
    pg += sx;
  }
  __syncthreads();

  // --- Phase C2: cooperative per-l reduction (sum, sumsq over 128 ch) ----
  {
    const int row = t >> 2, part = t & 3;    // row = sl2*32 + l2
    const int sl2 = row >> 5, l2 = row & 31;
    const short* yr = &s_d[row * 128 + part * 32];
    float s1 = 0.f, s2 = 0.f;
    #pragma unroll
    for (int i = 0; i < 32; i++){
      float v = b2f(yr[i]);
      s1 += v; s2 += v * v;
    }
    s1 += __shfl_xor(s1, 1); s2 += __shfl_xor(s2, 1);
    s1 += __shfl_xor(s1, 2); s2 += __shfl_xor(s2, 2);
    if (part == 0){ s_stat[sl2][l2][0] = s1; s_stat[sl2][l2][1] = s2; }
  }
  __syncthreads();

  // --- Phase C3: LN over 128 ch + wax -> per-axis Y (store, no RMW) ------
  float a0 = axw[0], a1 = axw[1], a2 = axw[2];
  float mxw = fmaxf(a0, fmaxf(a1, a2));
  float e0 = __expf(a0 - mxw), e1 = __expf(a1 - mxw), e2 = __expf(a2 - mxw);
  float wax = ((axis == 0) ? e0 : (axis == 1) ? e1 : e2) / (e0 + e1 + e2);
  const float pw = pnw[ch], pb = pnb[ch];

  __hip_bfloat16* py = Yax + (size_t)base * 128 + ch;
  #pragma unroll
  for (int l = 0; l < 32; l++){
    float ss1 = s_stat[sl][l][0];
    float ss2 = s_stat[sl][l][1];
    float mu = ss1 * (1.f / 128.f);
    float var = ss2 * (1.f / 128.f) - mu * mu;
    float rs = rsqrtf(fmaxf(var, 0.f) + 1e-5f);
    float yv = b2f(s_d[(sl * 32 + l) * 128 + ch]);
    float o = ((yv - mu) * rs * pw + pb) * wax;
    *(unsigned short*)py = (unsigned short)f2b(o);
    py += sx;
  }
}

// ---------------------------------------------------------------------------
// SINGLE out-projection GEMM over Y0+Y1+Y2 (MFMA is linear in B: three
// accumulating MFMAs sum the axes exactly) + residual finalize.
// ---------------------------------------------------------------------------
__global__ __launch_bounds__(256) void gemm_out_k(const __hip_bfloat16* __restrict__ Y0,
    const __hip_bfloat16* __restrict__ Y1, const __hip_bfloat16* __restrict__ Y2,
    const __hip_bfloat16* __restrict__ oW, const float* __restrict__ xres,
    const float* __restrict__ rsc, float* __restrict__ outp)
{
  const int t = threadIdx.x, wave = t >> 6, lane = t & 63, quad = lane >> 4, ln = lane & 15;
  const int pos0 = blockIdx.x * 64 + wave * 16;
  f32x4 acc[4];
  #pragma unroll
  for (int mt = 0; mt < 4; mt++) acc[mt] = (f32x4){0.f, 0.f, 0.f, 0.f};
  #pragma unroll
  for (int ks = 0; ks < 4; ks++){
    const size_t boffs = (size_t)(pos0 + ln) * 128 + ks * 32 + quad * 8;
    short8 bv0 = *(const short8*)&Y0[boffs];
    short8 bv1 = *(const short8*)&Y1[boffs];
    short8 bv2 = *(const short8*)&Y2[boffs];
    #pragma unroll
    for (int mt = 0; mt < 4; mt++){
      short8 a = *(const short8*)&oW[(mt * 16 + ln) * 128 + ks * 32 + quad * 8];
      acc[mt] = __builtin_amdgcn_mfma_f32_16x16x32_bf16(a, bv0, acc[mt], 0, 0, 0);
      acc[mt] = __builtin_amdgcn_mfma_f32_16x16x32_bf16(a, bv1, acc[mt], 0, 0, 0);
      acc[mt] = __builtin_amdgcn_mfma_f32_16x16x32_bf16(a, bv2, acc[mt], 0, 0, 0);
    }
  }
  float rs = rsc[0];
  const int pos = pos0 + ln;
  const int bb = pos >> 15, hwd = pos & 32767;
  #pragma unroll
  for (int mt = 0; mt < 4; mt++){
    #pragma unroll
    for (int reg = 0; reg < 4; reg++){
      int co = mt * 16 + quad * 4 + reg;
      size_t idx = (((size_t)(bb * 64 + co)) << 15) + hwd;
      outp[idx] = xres[idx] + rs * acc[mt][reg];
    }
  }
}

// ---------------------------------------------------------------------------
extern "C" void kernel_launch(void* const* d_in, const int* in_sizes, int n_in,
                              void* d_out, int out_size, void* d_ws, size_t ws_size,
                              hipStream_t stream)
{
  const float* x      = (const float*)d_in[0];
  const float* cr1w   = (const float*)d_in[1];
  const float* cr2w   = (const float*)d_in[3];
  const float* ln_w   = (const float*)d_in[5];
  const float* ln_b   = (const float*)d_in[6];
  const float* left_w = (const float*)d_in[7];
  const float* c1dw   = (const float*)d_in[8];
  const float* c1db   = (const float*)d_in[9];
  const float* dw     = (const float*)d_in[10];
  const float* db     = (const float*)d_in[11];
  const float* bpw    = (const float*)d_in[12];
  const float* cpw    = (const float*)d_in[13];
  const float* alog   = (const float*)d_in[14];
  const float* rw     = (const float*)d_in[15];
  const float* pnw    = (const float*)d_in[16];
  const float* pnb    = (const float*)d_in[17];
  const float* ow     = (const float*)d_in[18];
  const float* rsc    = (const float*)d_in[19];
  const float* axw    = (const float*)d_in[20];
  float* out = (float*)d_out;                       // final out; ybuf alias pre-gemm_out
  float* wsf = (float*)d_ws;

  __hip_bfloat16* ybuf = (__hip_bfloat16*)d_out;               // conv out bf16 (33.5MB < 67MB)
  __hip_bfloat16* x1b  = (__hip_bfloat16*)wsf;                 // x1 bf16 (dead after apply_ln -> Y0)
  float* stats1 = wsf + 4194304;                               // 256 f (sum | sumsq)
  float* stats2 = wsf + 4194560;                               // 256 f
  float* negA2  = wsf + 4194816;                               // 16 f
  __hip_bfloat16* W4a  = (__hip_bfloat16*)(wsf + 4195072);     // 110,592 bf16
  __hip_bfloat16* W4b  = W4a + 110592;                         // ends f-off 4,305,664
  __hip_bfloat16* Wlr  = (__hip_bfloat16*)(wsf + 4305664);     // 16,384 bf16
  __hip_bfloat16* Wdbc = (__hip_bfloat16*)(wsf + 4313856);     // 20,480 bf16
  __hip_bfloat16* oWp  = (__hip_bfloat16*)(wsf + 4324096);     // 8,192 bf16
  __hip_bfloat16* xpad = (__hip_bfloat16*)(wsf + 4328192);     // 5,030,912 bf16
  __hip_bfloat16* lnx  = xpad;                                 // alias (post-conv)
  __hip_bfloat16* Lbuf = (__hip_bfloat16*)(wsf + 6843648);     // 8,388,608 bf16
  __hip_bfloat16* Gbuf = (__hip_bfloat16*)(wsf + 11037952);    // 8,388,608 bf16
  __hip_bfloat16* Y0   = (__hip_bfloat16*)wsf;                 // (x1b region, post-apply_ln)
  __hip_bfloat16* Y1   = (__hip_bfloat16*)(wsf + 15232256);    // 8,388,608 bf16
  __hip_bfloat16* Y2   = (__hip_bfloat16*)(wsf + 19426560);    // 8,388,608 bf16

  setup_k<<<3498, 256, 0, stream>>>((uint4*)xpad, cr1w, cr2w, left_w, rw, dw, bpw, cpw, ow,
                                    alog, W4a, W4b, Wlr, Wdbc, oWp, negA2,
                                    (uint4*)stats1);

  // conv-res block 1 (stats fused into conv epilogue)
  pack_k<<<2048, 256, 0, stream>>>(x, xpad);
  conv_mfma_k<<<512, 256, 0, stream>>>(xpad, W4a, ybuf, stats1);
  apply_pack_k<<<2048, 256, 0, stream>>>(x, ybuf, stats1, x1b, xpad);
  // conv-res block 2 (fused apply + LayerNorm; x2 never materialized)
  conv_mfma_k<<<512, 256, 0, stream>>>(xpad, W4b, ybuf, stats2);
  apply_ln_k<<<2048, 256, 0, stream>>>(x1b, ybuf, stats2, ln_w, ln_b, lnx);

  // mamba: axis-independent projection once
  gemm_lr_k<<<1024, 256, 0, stream>>>(lnx, Wlr, Lbuf, Gbuf);

  // ALL 3 axes in one launch (axis = bid%3); per-axis Y buffers, no RMW
  dbcscan_k<<<3072, 256, 0, stream>>>(Lbuf, c1dw, c1db, Wdbc, db, Gbuf, negA2,
                                      pnw, pnb, axw, Y0, Y1, Y2);

  // single out-projection over Y0+Y1+Y2 + residual finalize
  gemm_out_k<<<1024, 256, 0, stream>>>(Y0, Y1, Y2, oWp, x, rsc, out);
}

// Round 17
// 394.041 us; speedup vs baseline: 1.0655x; 1.0403x over previous
//
#include <hip/hip_runtime.h>
#include <hip/hip_bf16.h>
#include <math.h>
#include <stdint.h>

// ---------------------------------------------------------------------------
// Full U-Mamba block. R26: conv LDS double-buffer + apply_ln⊕gemm_lr fusion.
//   (1) conv_mfma_k: 2-set LDS dbuf. Per stage: barrier -> issue gld(next)
//       -> compute(cur). The barrier's implicit vmcnt(0) drain now waits on
//       loads that had a full 16-MFMA phase to land (R25: zero time).
//       27 barriers/block (was 54), each ~free. LDS 24->48KB (2 blocks/CU
//       grid-capped, unaffected).
//   (2) ln_lr_k: apply_ln + gemm_lr fused on shared 64-pos tiles; lnx tile
//       lives in LDS bf16 [64][68] (pad kills bank period). Removes 16.8MB
//       HBM + 1 launch; lnx never in HBM.
// Kept: R17/R18 HW transcendentals, R20-R22 fused 3-axis dbcscan, R23 bf16
// glue + short8, R24 fused conv stats, R25 2-ch-group conv stages.
// ---------------------------------------------------------------------------

typedef __attribute__((ext_vector_type(8))) short short8;   // 8 bf16 = 4 VGPR
typedef __attribute__((ext_vector_type(4))) float f32x4;

__device__ __forceinline__ float siluf(float x){ return x * (1.0f / (1.0f + __expf(-x))); }
__device__ __forceinline__ float softplusf(float x){ return fmaxf(x, 0.0f) + log1pf(__expf(-fabsf(x))); }
// HW-transcendental softplus: v_exp_f32 + v_log_f32 (both ~1ulp), ~6 VALU ops.
__device__ __forceinline__ float softplus_hw(float x){
  float t = __builtin_amdgcn_exp2f(-fabsf(x) * 1.44269504088896f);
  return fmaxf(x, 0.0f) + 0.69314718055995f * __builtin_amdgcn_logf(1.0f + t);
}
__device__ __forceinline__ float b2f(short s){
  unsigned int u = ((unsigned int)(unsigned short)s) << 16;
  float f; __builtin_memcpy(&f, &u, 4); return f;
}
__device__ __forceinline__ short f2b(float v){
  __hip_bfloat16 h = __float2bfloat16(v);
  unsigned short u; __builtin_memcpy(&u, &h, 2); return (short)u;
}

// async global->LDS, 16B per lane; LDS dest is wave-uniform base + lane*16.
__device__ __forceinline__ void gld_lds16(const void* g, void* l){
  __builtin_amdgcn_global_load_lds(
      (__attribute__((address_space(1))) void*)(uintptr_t)g,
      (__attribute__((address_space(3))) void*)(uint32_t)(uintptr_t)l,
      16, 0, 0);
}

// ---------------------------------------------------------------------------
// One-shot setup: zero xpad | zero stats1/2 | pack conv weights a/b -> bf16 |
// mamba weight bf16 tables | negA2[s] = -softplus(A_log[s]) * log2(e).
// ---------------------------------------------------------------------------
__global__ __launch_bounds__(256) void setup_k(uint4* __restrict__ xz,
    const float* __restrict__ cr1w, const float* __restrict__ cr2w,
    const float* __restrict__ lw, const float* __restrict__ rwt,
    const float* __restrict__ dwt, const float* __restrict__ bw,
    const float* __restrict__ cwp, const float* __restrict__ owt,
    const float* __restrict__ alog,
    __hip_bfloat16* __restrict__ W4a, __hip_bfloat16* __restrict__ W4b,
    __hip_bfloat16* __restrict__ Wlr, __hip_bfloat16* __restrict__ Wd,
    __hip_bfloat16* __restrict__ oWp, float* __restrict__ negA2,
    uint4* __restrict__ statz)
{
  int i = blockIdx.x * 256 + threadIdx.x;
  if (i < 628864){ uint4 z; z.x = z.y = z.z = z.w = 0u; xz[i] = z; return; }
  i -= 628864;
  if (i < 110592){
    int tap = i >> 12, co = (i >> 6) & 63, ci = i & 63;
    W4a[i] = __float2bfloat16(cr1w[(co * 64 + ci) * 27 + tap]); return;
  }
  i -= 110592;
  if (i < 110592){
    int tap = i >> 12, co = (i >> 6) & 63, ci = i & 63;
    W4b[i] = __float2bfloat16(cr2w[(co * 64 + ci) * 27 + tap]); return;
  }
  i -= 110592;
  if (i < 16384){
    int row = i >> 6, c = i & 63;
    float v = (row < 128) ? lw[row * 64 + c] : rwt[(row - 128) * 64 + c];
    Wlr[i] = __float2bfloat16(v); return;
  }
  i -= 16384;
  if (i < 20480){
    int row = i >> 7, k = i & 127;
    float v = (row < 128) ? dwt[row * 128 + k]
            : (row < 144 ? bw[(row - 128) * 128 + k] : cwp[(row - 144) * 128 + k]);
    Wd[i] = __float2bfloat16(v); return;
  }
  i -= 20480;
  if (i < 8192){ oWp[i] = __float2bfloat16(owt[i]); return; }
  i -= 8192;
  if (i < 16){ negA2[i] = -softplusf(alog[i]) * 1.44269504088896f; return; }
  i -= 16;
  if (i < 128){ uint4 z; z.x = z.y = z.z = z.w = 0u; statz[i] = z; return; }
}

// ---------------------------------------------------------------------------
// Pack fp32 NCDHW -> padded channels-last bf16 [b][h+1][w+1][d+1][c] (conv1).
// ---------------------------------------------------------------------------
__global__ __launch_bounds__(256) void pack_k(const float* __restrict__ xin,
                                              __hip_bfloat16* __restrict__ xpad)
{
  __shared__ float lds[64 * 33];
  const int t = threadIdx.x, blk = blockIdx.x;
  const int b = blk >> 10, h = (blk >> 5) & 31, w = blk & 31;
  const size_t rbase = ((size_t)(b * 64) << 15) + h * 1024 + w * 32;
  #pragma unroll
  for (int r = 0; r < 8; r++){
    int c = r * 8 + (t >> 5), d = t & 31;
    lds[c * 33 + d] = xin[rbase + (size_t)c * 32768 + d];
  }
  __syncthreads();
  const size_t wbase = (size_t)b * 2515456 + (size_t)(h + 1) * 73984 + (w + 1) * 2176 + 64;
  #pragma unroll
  for (int r = 0; r < 8; r++){
    int d = r * 4 + (t >> 6), c = t & 63;
    xpad[wbase + d * 64 + c] = __float2bfloat16(lds[c * 33 + d]);
  }
}

// ---------------------------------------------------------------------------
// Conv3d implicit GEMM, bf16 MFMA 16x16x32, LDS double-buffered.
// R26: per stage: barrier -> gld(set next) -> 16 MFMAs(set cur). 27 barriers
// total; each barrier's vmcnt drain waits on loads issued a full compute
// phase earlier. Epilogue: bf16 y + fused InstanceNorm stats (R24).
// ---------------------------------------------------------------------------
__global__ __launch_bounds__(256) void conv_mfma_k(const __hip_bfloat16* __restrict__ xpad,
    const __hip_bfloat16* __restrict__ W4, __hip_bfloat16* __restrict__ y,
    float* __restrict__ stats)
{
  __shared__ short smem[24576];  // 2 sets x 12288: per set B[0,8192) A[8192,12288)

  const int t = threadIdx.x;
  const int wave = t >> 6, lane = t & 63;
  const int quad = lane >> 4, ln = lane & 15;

  const int blk = blockIdx.x;          // 512 blocks
  const int xcd = blk & 7, j = blk >> 3;
  const int b = j >> 5, jj = j & 31;
  const int h = xcd * 4 + (jj >> 3);
  const int w0 = (jj & 7) * 4;

  const int bcol = (lane >> 2) * 64 + (lane & 3) * 8;
  const __hip_bfloat16* Bg = xpad + (size_t)b * 2515456 + (size_t)h * 73984
                                  + (size_t)(w0 + wave) * 2176 + bcol;
  const __hip_bfloat16* Ag = W4 + wave * 1024 + bcol;

  f32x4 acc[2][4];
  #pragma unroll
  for (int jn = 0; jn < 2; jn++)
    #pragma unroll
    for (int m = 0; m < 4; m++) acc[jn][m] = (f32x4){0.f, 0.f, 0.f, 0.f};

  const int aoff = ln * 32 + quad * 8;
  const int boffl = wave * 2048 + ln * 32 + quad * 8;

  // prologue: stage tap 0 into set 0
  {
    short* S = &smem[0];
    gld_lds16(Bg,              S + wave * 2048);
    gld_lds16(Bg + 1024,       S + wave * 2048 + 512);
    gld_lds16(Bg + 32,         S + wave * 2048 + 1024);
    gld_lds16(Bg + 1024 + 32,  S + wave * 2048 + 1536);
    gld_lds16(Ag,              S + 8192 + wave * 512);
    gld_lds16(Ag + 32,         S + 8192 + 2048 + wave * 512);
  }
  int cur = 0;
  for (int t1 = 0; t1 < 27; t1++){
    __syncthreads();   // drains vmcnt -> set[cur] ready; set[cur^1] free
    if (t1 + 1 < 27){
      const int t2 = t1 + 1;
      const int ki = t2 / 9, kj = (t2 / 3) % 3, kk = t2 % 3;
      const int tapoff = ki * 73984 + kj * 2176 + kk * 64;
      short* S = &smem[(cur ^ 1) * 12288];
      gld_lds16(Bg + tapoff,             S + wave * 2048);
      gld_lds16(Bg + tapoff + 1024,      S + wave * 2048 + 512);
      gld_lds16(Bg + tapoff + 32,        S + wave * 2048 + 1024);
      gld_lds16(Bg + tapoff + 1024 + 32, S + wave * 2048 + 1536);
      gld_lds16(Ag + t2 * 4096,          S + 8192 + wave * 512);
      gld_lds16(Ag + t2 * 4096 + 32,     S + 8192 + 2048 + wave * 512);
    }
    const int sb = cur * 12288;
    // channel-group 0 (ci 0-31)
    {
      short8 a0 = *(const short8*)&smem[sb + 8192 + aoff];
      short8 a1 = *(const short8*)&smem[sb + 8192 + 512 + aoff];
      short8 a2 = *(const short8*)&smem[sb + 8192 + 1024 + aoff];
      short8 a3 = *(const short8*)&smem[sb + 8192 + 1536 + aoff];
      short8 b0 = *(const short8*)&smem[sb + boffl];
      short8 b1 = *(const short8*)&smem[sb + boffl + 512];
      acc[0][0] = __builtin_amdgcn_mfma_f32_16x16x32_bf16(a0, b0, acc[0][0], 0, 0, 0);
      acc[0][1] = __builtin_amdgcn_mfma_f32_16x16x32_bf16(a1, b0, acc[0][1], 0, 0, 0);
      acc[0][2] = __builtin_amdgcn_mfma_f32_16x16x32_bf16(a2, b0, acc[0][2], 0, 0, 0);
      acc[0][3] = __builtin_amdgcn_mfma_f32_16x16x32_bf16(a3, b0, acc[0][3], 0, 0, 0);
      acc[1][0] = __builtin_amdgcn_mfma_f32_16x16x32_bf16(a0, b1, acc[1][0], 0, 0, 0);
      acc[1][1] = __builtin_amdgcn_mfma_f32_16x16x32_bf16(a1, b1, acc[1][1], 0, 0, 0);
      acc[1][2] = __builtin_amdgcn_mfma_f32_16x16x32_bf16(a2, b1, acc[1][2], 0, 0, 0);
      acc[1][3] = __builtin_amdgcn_mfma_f32_16x16x32_bf16(a3, b1, acc[1][3], 0, 0, 0);
    }
    // channel-group 1 (ci 32-63)
    {
      short8 a0 = *(const short8*)&smem[sb + 8192 + 2048 + aoff];
      short8 a1 = *(const short8*)&smem[sb + 8192 + 2048 + 512 + aoff];
      short8 a2 = *(const short8*)&smem[sb + 8192 + 2048 + 1024 + aoff];
      short8 a3 = *(const short8*)&smem[sb + 8192 + 2048 + 1536 + aoff];
      short8 b0 = *(const short8*)&smem[sb + boffl + 1024];
      short8 b1 = *(const short8*)&smem[sb + boffl + 1536];
      acc[0][0] = __builtin_amdgcn_mfma_f32_16x16x32_bf16(a0, b0, acc[0][0], 0, 0, 0);
      acc[0][1] = __builtin_amdgcn_mfma_f32_16x16x32_bf16(a1, b0, acc[0][1], 0, 0, 0);
      acc[0][2] = __builtin_amdgcn_mfma_f32_16x16x32_bf16(a2, b0, acc[0][2], 0, 0, 0);
      acc[0][3] = __builtin_amdgcn_mfma_f32_16x16x32_bf16(a3, b0, acc[0][3], 0, 0, 0);
      acc[1][0] = __builtin_amdgcn_mfma_f32_16x16x32_bf16(a0, b1, acc[1][0], 0, 0, 0);
      acc[1][1] = __builtin_amdgcn_mfma_f32_16x16x32_bf16(a1, b1, acc[1][1], 0, 0, 0);
      acc[1][2] = __builtin_amdgcn_mfma_f32_16x16x32_bf16(a2, b1, acc[1][2], 0, 0, 0);
      acc[1][3] = __builtin_amdgcn_mfma_f32_16x16x32_bf16(a3, b1, acc[1][3], 0, 0, 0);
    }
    cur ^= 1;
  }

  const size_t sbase = (size_t)h * 1024 + (w0 + wave) * 32 + ln;
  #pragma unroll
  for (int jn = 0; jn < 2; jn++){
    #pragma unroll
    for (int mt = 0; mt < 4; mt++){
      #pragma unroll
      for (int reg = 0; reg < 4; reg++){
        int co = mt * 16 + quad * 4 + reg;
        y[(((size_t)(b * 64 + co)) << 15) + sbase + jn * 16] = __float2bfloat16(acc[jn][mt][reg]);
      }
    }
  }

  // --- fused InstanceNorm partial stats: (sum, sumsq) per channel --------
  __syncthreads();                 // all smem reads done; reuse as float
  float* sred = (float*)smem;      // [wave][quad][mt][reg][2] = 512 floats
  #pragma unroll
  for (int mt = 0; mt < 4; mt++){
    #pragma unroll
    for (int reg = 0; reg < 4; reg++){
      float a0 = acc[0][mt][reg], a1 = acc[1][mt][reg];
      float s = a0 + a1, s2 = a0 * a0 + a1 * a1;
      #pragma unroll
      for (int m = 1; m < 16; m <<= 1){
        s  += __shfl_xor(s, m);
        s2 += __shfl_xor(s2, m);
      }
      if (ln == 0){
        const int idx = (((wave * 4 + quad) * 4 + mt) * 4 + reg) * 2;
        sred[idx] = s; sred[idx + 1] = s2;
      }
    }
  }
  __syncthreads();
  if (t < 128){
    const int k = t & 1, reg = (t >> 1) & 3, mt = (t >> 3) & 3, q = t >> 5;
    float v = 0.f;
    #pragma unroll
    for (int wv = 0; wv < 4; wv++)
      v += sred[(((wv * 4 + q) * 4 + mt) * 4 + reg) * 2 + k];
    const int co = mt * 16 + q * 4 + reg;
    atomicAdd(&stats[k * 128 + b * 64 + co], v);
  }
}

// ---------------------------------------------------------------------------
// Fused: InstanceNorm-apply + LeakyReLU + residual -> x1b (bf16 NCDHW)
// AND bf16 channels-last re-pack into xpad. mu/rs derived from (sum,sumsq).
// ---------------------------------------------------------------------------
__global__ __launch_bounds__(256) void apply_pack_k(const float* __restrict__ xin,
    const __hip_bfloat16* __restrict__ y, const float* __restrict__ stats,
    __hip_bfloat16* __restrict__ x1b, __hip_bfloat16* __restrict__ xpad)
{
  __shared__ float lds[64 * 33];
  const int t = threadIdx.x, blk = blockIdx.x;
  const int b = blk >> 10, h = (blk >> 5) & 31, w = blk & 31;
  const size_t rbase = ((size_t)(b * 64) << 15) + h * 1024 + w * 32;
  const int c = t >> 2, d0 = (t & 3) * 8;
  const float s1v = stats[b * 64 + c], s2v = stats[128 + b * 64 + c];
  const float mu = s1v * (1.0f / 32768.0f);
  const float var = s2v * (1.0f / 32768.0f) - mu * mu;
  const float rs = rsqrtf(fmaxf(var, 0.f) + 1e-5f);
  const size_t idx = rbase + (size_t)c * 32768 + d0;
  short8 yv = *(const short8*)&y[idx];
  float4 xa = *(const float4*)&xin[idx];
  float4 xb = *(const float4*)&xin[idx + 4];
  short8 o;
  #pragma unroll
  for (int jj = 0; jj < 8; jj++){
    float v = (b2f(yv[jj]) - mu) * rs;
    v = (v >= 0.0f) ? v : 0.01f * v;
    v += (jj < 4) ? ((const float*)&xa)[jj] : ((const float*)&xb)[jj - 4];
    o[jj] = f2b(v);
    lds[c * 33 + d0 + jj] = v;
  }
  *(short8*)&x1b[idx] = o;
  __syncthreads();
  const size_t wbase = (size_t)b * 2515456 + (size_t)(h + 1) * 73984 + (w + 1) * 2176 + 64;
  #pragma unroll
  for (int r = 0; r < 8; r++){
    int d = r * 4 + (t >> 6), cc = t & 63;
    xpad[wbase + d * 64 + cc] = __float2bfloat16(lds[cc * 33 + d]);
  }
}

// ---------------------------------------------------------------------------
// FUSED: InstanceNorm-apply + LeakyReLU + residual + LayerNorm over C
// + GEMM [64pos,64] x [64,256] -> Lbuf/Gbuf. lnx tile lives only in LDS.
// One block = 64 positions (w pair x 32 d). Grid 1024.
// ---------------------------------------------------------------------------
__global__ __launch_bounds__(256) void ln_lr_k(const __hip_bfloat16* __restrict__ x1b,
    const __hip_bfloat16* __restrict__ y, const float* __restrict__ stats,
    const float* __restrict__ lnw, const float* __restrict__ lnb,
    const __hip_bfloat16* __restrict__ Wlr, __hip_bfloat16* __restrict__ Lb,
    __hip_bfloat16* __restrict__ Gb)
{
  __shared__ float lds_v[2][64 * 33];        // [w_loc][c*33+d]
  __shared__ float s_mu[64], s_rs[64];       // per pos_loc = w_loc*32+d
  __shared__ short s_ln[64 * 68];            // lnx tile bf16 [pos_loc][68]

  const int t = threadIdx.x, blk = blockIdx.x;   // 1024 blocks x 64 pos
  const int b = blk >> 9;
  const int h = (blk >> 4) & 31;
  const int w0 = (blk & 15) * 2;

  // Phase 1: IN-apply + leaky + residual for both w's -> lds_v (f32)
  const int c = t >> 2, d0 = (t & 3) * 8;
  const float s1v = stats[b * 64 + c], s2v = stats[128 + b * 64 + c];
  const float mu0 = s1v * (1.0f / 32768.0f);
  const float var0 = s2v * (1.0f / 32768.0f) - mu0 * mu0;
  const float rs0 = rsqrtf(fmaxf(var0, 0.f) + 1e-5f);
  #pragma unroll
  for (int wl = 0; wl < 2; wl++){
    const size_t rbase = ((size_t)(b * 64) << 15) + h * 1024 + (w0 + wl) * 32;
    const size_t idx = rbase + (size_t)c * 32768 + d0;
    short8 yv = *(const short8*)&y[idx];
    short8 xv = *(const short8*)&x1b[idx];
    #pragma unroll
    for (int jj = 0; jj < 8; jj++){
      float v = (b2f(yv[jj]) - mu0) * rs0;
      v = (v >= 0.0f) ? v : 0.01f * v;
      lds_v[wl][c * 33 + d0 + jj] = v + b2f(xv[jj]);
    }
  }
  __syncthreads();

  // Phase 2: LN stats per position (64 positions, over 64 channels)
  if (t < 64){
    const int wl = t >> 5, d = t & 31;
    float s = 0.f, s2 = 0.f;
    for (int cc = 0; cc < 64; cc++){
      float v = lds_v[wl][cc * 33 + d];
      s += v; s2 += v * v;
    }
    float mu = s * (1.f / 64.f);
    float var = s2 * (1.f / 64.f) - mu * mu;
    s_mu[t] = mu; s_rs[t] = rsqrtf(var + 1e-5f);
  }
  __syncthreads();

  // Phase 3: build bf16 lnx tile [pos_loc][68]
  {
    const int pos_loc = t >> 2, c0 = (t & 3) * 16;
    const int wl = pos_loc >> 5, d = pos_loc & 31;
    const float mu = s_mu[pos_loc], rs = s_rs[pos_loc];
    #pragma unroll
    for (int k = 0; k < 16; k++){
      const int cc = c0 + k;
      s_ln[pos_loc * 68 + cc] = f2b((lds_v[wl][cc * 33 + d] - mu) * rs * lnw[cc] + lnb[cc]);
    }
  }
  __syncthreads();

  // Phase 4: GEMM from LDS tile -> Lb (raw) / Gb (silu)
  const int wave = t >> 6, lane = t & 63, quad = lane >> 4, ln = lane & 15;
  const int pos0 = blk * 64 + wave * 16;
  f32x4 acc[16];
  #pragma unroll
  for (int nt = 0; nt < 16; nt++) acc[nt] = (f32x4){0.f, 0.f, 0.f, 0.f};
  #pragma unroll
  for (int ks = 0; ks < 2; ks++){
    short8 a = *(const short8*)&s_ln[(wave * 16 + ln) * 68 + ks * 32 + quad * 8];
    #pragma unroll
    for (int nt = 0; nt < 16; nt++){
      short8 bv = *(const short8*)&Wlr[(nt * 16 + ln) * 64 + ks * 32 + quad * 8];
      acc[nt] = __builtin_amdgcn_mfma_f32_16x16x32_bf16(a, bv, acc[nt], 0, 0, 0);
    }
  }
  #pragma unroll
  for (int nt = 0; nt < 16; nt++){
    int col = nt * 16 + ln;
    #pragma unroll
    for (int reg = 0; reg < 4; reg++){
      int pos = pos0 + quad * 4 + reg;
      float v = acc[nt][reg];
      if (col < 128) Lb[(size_t)pos * 128 + col] = __float2bfloat16(v);
      else           Gb[(size_t)pos * 128 + col - 128] = __float2bfloat16(siluf(v));
    }
  }
}

// ---------------------------------------------------------------------------
// FUSED per-axis: conv1d(k=4)+silu -> LDS | GEMM [64,128]x[128,160] -> LDS |
// selective scan + gate + post-LN + wax-weight -> per-axis Y buffer.
// ONE launch covers all 3 axes: axis = blockIdx.x % 3, j = blockIdx.x / 3.
// Gated-y ALIASES the delta array s_d. B/C stored bf16 (R19 numerics).
// LDS 37.5KB -> 4 blocks/CU. dbc/xl never touch HBM; Y stores only (no RMW).
// ---------------------------------------------------------------------------
__global__ __launch_bounds__(256) void dbcscan_k(const __hip_bfloat16* __restrict__ Lb,
    const float* __restrict__ cw, const float* __restrict__ cb,
    const __hip_bfloat16* __restrict__ Wd, const float* __restrict__ db,
    const __hip_bfloat16* __restrict__ Gb, const float* __restrict__ negA2,
    const float* __restrict__ pnw, const float* __restrict__ pnb,
    const float* __restrict__ axw,
    __hip_bfloat16* __restrict__ Y0, __hip_bfloat16* __restrict__ Y1,
    __hip_bfloat16* __restrict__ Y2)
{
  __shared__ short s_xl[64 * 136];           // silu(conv1d) bf16, row = sl*32+l
  __shared__ short s_d[64 * 128];            // delta bf16; REUSED as gated-y
  __shared__ short s_Bh[2][32][16];          // B bf16 (R19 numerics)
  __shared__ short s_Ch[2][32][16];          // C bf16
  __shared__ float s_stat[2][32][2];         // per-l {sum, sumsq}

  const int t = threadIdx.x;
  const int bid = blockIdx.x;
  const int axis = bid % 3;                  // interleave axes across dispatch
  const int j = bid / 3;                     // 0..1023 (seq pair)
  int sigma;
  if (axis == 0)      sigma = 1024;
  else if (axis == 1) sigma = 32;
  else                sigma = 1;
  __hip_bfloat16* Yax = (axis == 0) ? Y0 : (axis == 1) ? Y1 : Y2;

  // bases for this block's two sequences
  int bases[2];
  #pragma unroll
  for (int s = 0; s < 2; s++){
    const int seq = j * 2 + s;
    const int b = seq >> 10, r1 = (seq >> 5) & 31, r0 = seq & 31;
    if (axis == 0)      bases[s] = b * 32768 + r1 * 32 + r0;
    else if (axis == 1) bases[s] = b * 32768 + r1 * 1024 + r0;
    else                bases[s] = b * 32768 + r1 * 1024 + r0 * 32;
  }

  // --- Phase A: conv1d(k=4) + silu -> s_xl --------------------------------
  {
    const int c0 = (t & 15) * 8;
    const int pibase = t >> 4;
    float4 w4[8]; float cbv[8];
    #pragma unroll
    for (int c = 0; c < 8; c++){ w4[c] = *(const float4*)&cw[(c0 + c) * 4]; cbv[c] = cb[c0 + c]; }
    #pragma unroll
    for (int r = 0; r < 4; r++){
      const int row = pibase + r * 16;          // 0..63
      const int sl_ = row >> 5, l = row & 31;
      const int pos = bases[sl_] + l * sigma;
      float acc[8];
      #pragma unroll
      for (int c = 0; c < 8; c++) acc[c] = cbv[c];
      #pragma unroll
      for (int jt = 0; jt < 4; jt++){
        const int off = 3 - jt;
        if (l >= off){
          short8 lv = *(const short8*)&Lb[(size_t)(pos - off * sigma) * 128 + c0];
          #pragma unroll
          for (int c = 0; c < 8; c++){
            float wv = (jt == 0) ? w4[c].x : (jt == 1) ? w4[c].y : (jt == 2) ? w4[c].z : w4[c].w;
            acc[c] += wv * b2f(lv[c]);
          }
        }
      }
      short8 o;
      #pragma unroll
      for (int c = 0; c < 8; c++) o[c] = f2b(siluf(acc[c]));
      *(short8*)&s_xl[row * 136 + c0] = o;
    }
  }
  __syncthreads();

  // --- Phase B: GEMM [64,128] x [128,160]; epilogue -> s_d / s_Bh / s_Ch --
  const int wave = t >> 6, lane = t & 63, quad = lane >> 4, ln = lane & 15;
  {
    const int rowb = (wave * 16 + ln) * 136;
    f32x4 acc2[10];
    #pragma unroll
    for (int nt = 0; nt < 10; nt++) acc2[nt] = (f32x4){0.f, 0.f, 0.f, 0.f};
    #pragma unroll
    for (int ks = 0; ks < 4; ks++){
      short8 a = *(const short8*)&s_xl[rowb + ks * 32 + quad * 8];
      #pragma unroll
      for (int nt = 0; nt < 10; nt++){
        short8 bv = *(const short8*)&Wd[(nt * 16 + ln) * 128 + ks * 32 + quad * 8];
        acc2[nt] = __builtin_amdgcn_mfma_f32_16x16x32_bf16(a, bv, acc2[nt], 0, 0, 0);
      }
    }
    const int row0 = wave * 16 + quad * 4;
    #pragma unroll
    for (int nt = 0; nt < 10; nt++){
      const int col = nt * 16 + ln;
      const bool isd = col < 128;
      const float dbv = isd ? db[col] : 0.f;
      #pragma unroll
      for (int reg = 0; reg < 4; reg++){
        const int row = row0 + reg;
        float v = acc2[nt][reg];
        if (isd){
          v = fminf(fmaxf(softplus_hw(v + dbv), 1e-4f), 10.f);
          s_d[row * 128 + col] = f2b(v);
        } else {
          const int sl_ = row >> 5, l = row & 31, cc = col - 128;
          if (cc < 16) s_Bh[sl_][l][cc] = f2b(v);
          else         s_Ch[sl_][l][cc - 16] = f2b(v);
        }
      }
    }
  }

  // scan setup
  float A2[16], h[16];
  #pragma unroll
  for (int s = 0; s < 16; s++){ A2[s] = negA2[s]; h[s] = 0.f; }
  const int sl = wave >> 1;                  // seq_local 0/1
  const int half = wave & 1;                 // channel half 0/1
  const int ch = half * 64 + lane;
  const int base = bases[sl];
  const size_t sx = (size_t)sigma * 128;
  const __hip_bfloat16* pg = Gb + (size_t)base * 128 + ch;

  __syncthreads();

  // --- Phase C1: serial scan; dt/xt/B/C from LDS; g from global ----------
  unsigned short gu = *(const unsigned short*)pg;
  #pragma unroll
  for (int l = 0; l < 32; l++){
    unsigned short ngu = 0;
    if (l + 1 < 32) ngu = *(const unsigned short*)(pg + sx);
    const int row = sl * 32 + l;
    float dt = b2f(s_d[row * 128 + ch]);
    float xt = b2f(s_xl[row * 136 + ch]);
    float g = b2f((short)gu);
    float dx = dt * xt;
    short8 Bv0 = *(const short8*)&s_Bh[sl][l][0];
    short8 Bv1 = *(const short8*)&s_Bh[sl][l][8];
    short8 Cv0 = *(const short8*)&s_Ch[sl][l][0];
    short8 Cv1 = *(const short8*)&s_Ch[sl][l][8];
    float y = 0.f;
    #pragma unroll
    for (int s = 0; s < 16; s++){
      const float Bf = b2f((s < 8) ? Bv0[s] : Bv1[s - 8]);
      const float Cf = b2f((s < 8) ? Cv0[s] : Cv1[s - 8]);
      h[s] = __builtin_amdgcn_exp2f(dt * A2[s]) * h[s] + dx * Bf;
      y += h[s] * Cf;
    }
    s_d[row * 128 + ch] = f2b(y * g);        // alias write (gated y)
    gu = ngu;
    pg += sx;
  }
  __syncthreads();

  // --- Phase C2: cooperative per-l reduction (sum, sumsq over 128 ch) ----
  {
    const int row = t >> 2, part = t & 3;    // row = sl2*32 + l2
    const int sl2 = row >> 5, l2 = row & 31;
    const short* yr = &s_d[row * 128 + part * 32];
    float s1 = 0.f, s2 = 0.f;
    #pragma unroll
    for (int i = 0; i < 32; i++){
      float v = b2f(yr[i]);
      s1 += v; s2 += v * v;
    }
    s1 += __shfl_xor(s1, 1); s2 += __shfl_xor(s2, 1);
    s1 += __shfl_xor(s1, 2); s2 += __shfl_xor(s2, 2);
    if (part == 0){ s_stat[sl2][l2][0] = s1; s_stat[sl2][l2][1] = s2; }
  }
  __syncthreads();

  // --- Phase C3: LN over 128 ch + wax -> per-axis Y (store, no RMW) ------
  float a0 = axw[0], a1 = axw[1], a2 = axw[2];
  float mxw = fmaxf(a0, fmaxf(a1, a2));
  float e0 = __expf(a0 - mxw), e1 = __expf(a1 - mxw), e2 = __expf(a2 - mxw);
  float wax = ((axis == 0) ? e0 : (axis == 1) ? e1 : e2) / (e0 + e1 + e2);
  const float pw = pnw[ch], pb = pnb[ch];

  __hip_bfloat16* py = Yax + (size_t)base * 128 + ch;
  #pragma unroll
  for (int l = 0; l < 32; l++){
    float ss1 = s_stat[sl][l][0];
    float ss2 = s_stat[sl][l][1];
    float mu = ss1 * (1.f / 128.f);
    float var = ss2 * (1.f / 128.f) - mu * mu;
    float rs = rsqrtf(fmaxf(var, 0.f) + 1e-5f);
    float yv = b2f(s_d[(sl * 32 + l) * 128 + ch]);
    float o = ((yv - mu) * rs * pw + pb) * wax;
    *(unsigned short*)py = (unsigned short)f2b(o);
    py += sx;
  }
}

// ---------------------------------------------------------------------------
// SINGLE out-projection GEMM over Y0+Y1+Y2 (MFMA is linear in B: three
// accumulating MFMAs sum the axes exactly) + residual finalize.
// ---------------------------------------------------------------------------
__global__ __launch_bounds__(256) void gemm_out_k(const __hip_bfloat16* __restrict__ Y0,
    const __hip_bfloat16* __restrict__ Y1, const __hip_bfloat16* __restrict__ Y2,
    const __hip_bfloat16* __restrict__ oW, const float* __restrict__ xres,
    const float* __restrict__ rsc, float* __restrict__ outp)
{
  const int t = threadIdx.x, wave = t >> 6, lane = t & 63, quad = lane >> 4, ln = lane & 15;
  const int pos0 = blockIdx.x * 64 + wave * 16;
  f32x4 acc[4];
  #pragma unroll
  for (int mt = 0; mt < 4; mt++) acc[mt] = (f32x4){0.f, 0.f, 0.f, 0.f};
  #pragma unroll
  for (int ks = 0; ks < 4; ks++){
    const size_t boffs = (size_t)(pos0 + ln) * 128 + ks * 32 + quad * 8;
    short8 bv0 = *(const short8*)&Y0[boffs];
    short8 bv1 = *(const short8*)&Y1[boffs];
    short8 bv2 = *(const short8*)&Y2[boffs];
    #pragma unroll
    for (int mt = 0; mt < 4; mt++){
      short8 a = *(const short8*)&oW[(mt * 16 + ln) * 128 + ks * 32 + quad * 8];
      acc[mt] = __builtin_amdgcn_mfma_f32_16x16x32_bf16(a, bv0, acc[mt], 0, 0, 0);
      acc[mt] = __builtin_amdgcn_mfma_f32_16x16x32_bf16(a, bv1, acc[mt], 0, 0, 0);
      acc[mt] = __builtin_amdgcn_mfma_f32_16x16x32_bf16(a, bv2, acc[mt], 0, 0, 0);
    }
  }
  float rs = rsc[0];
  const int pos = pos0 + ln;
  const int bb = pos >> 15, hwd = pos & 32767;
  #pragma unroll
  for (int mt = 0; mt < 4; mt++){
    #pragma unroll
    for (int reg = 0; reg < 4; reg++){
      int co = mt * 16 + quad * 4 + reg;
      size_t idx = (((size_t)(bb * 64 + co)) << 15) + hwd;
      outp[idx] = xres[idx] + rs * acc[mt][reg];
    }
  }
}

// ---------------------------------------------------------------------------
extern "C" void kernel_launch(void* const* d_in, const int* in_sizes, int n_in,
                              void* d_out, int out_size, void* d_ws, size_t ws_size,
                              hipStream_t stream)
{
  const float* x      = (const float*)d_in[0];
  const float* cr1w   = (const float*)d_in[1];
  const float* cr2w   = (const float*)d_in[3];
  const float* ln_w   = (const float*)d_in[5];
  const float* ln_b   = (const float*)d_in[6];
  const float* left_w = (const float*)d_in[7];
  const float* c1dw   = (const float*)d_in[8];
  const float* c1db   = (const float*)d_in[9];
  const float* dw     = (const float*)d_in[10];
  const float* db     = (const float*)d_in[11];
  const float* bpw    = (const float*)d_in[12];
  const float* cpw    = (const float*)d_in[13];
  const float* alog   = (const float*)d_in[14];
  const float* rw     = (const float*)d_in[15];
  const float* pnw    = (const float*)d_in[16];
  const float* pnb    = (const float*)d_in[17];
  const float* ow     = (const float*)d_in[18];
  const float* rsc    = (const float*)d_in[19];
  const float* axw    = (const float*)d_in[20];
  float* out = (float*)d_out;                       // final out; ybuf alias pre-gemm_out
  float* wsf = (float*)d_ws;

  __hip_bfloat16* ybuf = (__hip_bfloat16*)d_out;               // conv out bf16 (33.5MB < 67MB)
  __hip_bfloat16* x1b  = (__hip_bfloat16*)wsf;                 // x1 bf16 (dead after ln_lr -> Y0)
  float* stats1 = wsf + 4194304;                               // 256 f (sum | sumsq)
  float* stats2 = wsf + 4194560;                               // 256 f
  float* negA2  = wsf + 4194816;                               // 16 f
  __hip_bfloat16* W4a  = (__hip_bfloat16*)(wsf + 4195072);     // 110,592 bf16
  __hip_bfloat16* W4b  = W4a + 110592;                         // ends f-off 4,305,664
  __hip_bfloat16* Wlr  = (__hip_bfloat16*)(wsf + 4305664);     // 16,384 bf16
  __hip_bfloat16* Wdbc = (__hip_bfloat16*)(wsf + 4313856);     // 20,480 bf16
  __hip_bfloat16* oWp  = (__hip_bfloat16*)(wsf + 4324096);     // 8,192 bf16
  __hip_bfloat16* xpad = (__hip_bfloat16*)(wsf + 4328192);     // 5,030,912 bf16
  __hip_bfloat16* Lbuf = (__hip_bfloat16*)(wsf + 6843648);     // 8,388,608 bf16
  __hip_bfloat16* Gbuf = (__hip_bfloat16*)(wsf + 11037952);    // 8,388,608 bf16
  __hip_bfloat16* Y0   = (__hip_bfloat16*)wsf;                 // (x1b region, post-ln_lr)
  __hip_bfloat16* Y1   = (__hip_bfloat16*)(wsf + 15232256);    // 8,388,608 bf16
  __hip_bfloat16* Y2   = (__hip_bfloat16*)(wsf + 19426560);    // 8,388,608 bf16

  setup_k<<<3498, 256, 0, stream>>>((uint4*)xpad, cr1w, cr2w, left_w, rw, dw, bpw, cpw, ow,
                                    alog, W4a, W4b, Wlr, Wdbc, oWp, negA2,
                                    (uint4*)stats1);

  // conv-res block 1 (stats fused into conv epilogue)
  pack_k<<<2048, 256, 0, stream>>>(x, xpad);
  conv_mfma_k<<<512, 256, 0, stream>>>(xpad, W4a, ybuf, stats1);
  apply_pack_k<<<2048, 256, 0, stream>>>(x, ybuf, stats1, x1b, xpad);
  // conv-res block 2 + fused LN + left/right projection (lnx never in HBM)
  conv_mfma_k<<<512, 256, 0, stream>>>(xpad, W4b, ybuf, stats2);
  ln_lr_k<<<1024, 256, 0, stream>>>(x1b, ybuf, stats2, ln_w, ln_b, Wlr, Lbuf, Gbuf);

  // ALL 3 axes in one launch (axis = bid%3); per-axis Y buffers, no RMW
  dbcscan_k<<<3072, 256, 0, stream>>>(Lbuf, c1dw, c1db, Wdbc, db, Gbuf, negA2,
                                      pnw, pnb, axw, Y0, Y1, Y2);

  // single out-projection over Y0+Y1+Y2 + residual finalize
  gemm_out_k<<<1024, 256, 0, stream>>>(Y0, Y1, Y2, oWp, x, rsc, out);
}

// Round 19
// 388.534 us; speedup vs baseline: 1.0806x; 1.0142x over previous
//
#include <hip/hip_runtime.h>
#include <hip/hip_bf16.h>
#include <math.h>
#include <stdint.h>

// ---------------------------------------------------------------------------
// Full U-Mamba block. R27b: resubmit of R27 (container-acquisition infra
// failure; same signature as R16/R16b which ran fine unchanged later).
//   dbcscan is issue-bound (VALUBusy 74%, stable 183us). C1 per-l arithmetic
//   = 64 scalar VALU (4x16 states) + 16 trans. States packed in pairs
//   (f32x2 h2[8]): LLVM emits v_pk_mul/fma_f32 for <2 x float> on CDNA ->
//   32 packed ops. bf16 pair unpack: u<<16 (lo) / u&0xffff0000 (hi), 1
//   op/float, pre-paired. exp2 stays scalar (trans). C1 VALU issue -35%.
// Kept: R17/R18 HW transcendentals, R20-R22 fused 3-axis dbcscan, R23 bf16
// glue + short8, R24 fused conv stats, R25/R26 dbuf conv, R26 ln_lr fusion.
// ---------------------------------------------------------------------------

typedef __attribute__((ext_vector_type(8))) short short8;   // 8 bf16 = 4 VGPR
typedef __attribute__((ext_vector_type(4))) float f32x4;
typedef __attribute__((ext_vector_type(2))) float f32x2;

__device__ __forceinline__ float siluf(float x){ return x * (1.0f / (1.0f + __expf(-x))); }
__device__ __forceinline__ float softplusf(float x){ return fmaxf(x, 0.0f) + log1pf(__expf(-fabsf(x))); }
// HW-transcendental softplus: v_exp_f32 + v_log_f32 (both ~1ulp), ~6 VALU ops.
__device__ __forceinline__ float softplus_hw(float x){
  float t = __builtin_amdgcn_exp2f(-fabsf(x) * 1.44269504088896f);
  return fmaxf(x, 0.0f) + 0.69314718055995f * __builtin_amdgcn_logf(1.0f + t);
}
__device__ __forceinline__ float b2f(short s){
  unsigned int u = ((unsigned int)(unsigned short)s) << 16;
  float f; __builtin_memcpy(&f, &u, 4); return f;
}
__device__ __forceinline__ short f2b(float v){
  __hip_bfloat16 h = __float2bfloat16(v);
  unsigned short u; __builtin_memcpy(&u, &h, 2); return (short)u;
}
// unpack u32 holding 2 bf16 -> f32x2 {elem_lo, elem_hi}; 1 VALU op per float.
__device__ __forceinline__ f32x2 bf2x(unsigned int u){
  unsigned int lo = u << 16;
  unsigned int hi = u & 0xffff0000u;
  float fl, fh;
  __builtin_memcpy(&fl, &lo, 4);
  __builtin_memcpy(&fh, &hi, 4);
  return (f32x2){fl, fh};
}

// async global->LDS, 16B per lane; LDS dest is wave-uniform base + lane*16.
__device__ __forceinline__ void gld_lds16(const void* g, void* l){
  __builtin_amdgcn_global_load_lds(
      (__attribute__((address_space(1))) void*)(uintptr_t)g,
      (__attribute__((address_space(3))) void*)(uint32_t)(uintptr_t)l,
      16, 0, 0);
}

// ---------------------------------------------------------------------------
// One-shot setup: zero xpad | zero stats1/2 | pack conv weights a/b -> bf16 |
// mamba weight bf16 tables | negA2[s] = -softplus(A_log[s]) * log2(e).
// ---------------------------------------------------------------------------
__global__ __launch_bounds__(256) void setup_k(uint4* __restrict__ xz,
    const float* __restrict__ cr1w, const float* __restrict__ cr2w,
    const float* __restrict__ lw, const float* __restrict__ rwt,
    const float* __restrict__ dwt, const float* __restrict__ bw,
    const float* __restrict__ cwp, const float* __restrict__ owt,
    const float* __restrict__ alog,
    __hip_bfloat16* __restrict__ W4a, __hip_bfloat16* __restrict__ W4b,
    __hip_bfloat16* __restrict__ Wlr, __hip_bfloat16* __restrict__ Wd,
    __hip_bfloat16* __restrict__ oWp, float* __restrict__ negA2,
    uint4* __restrict__ statz)
{
  int i = blockIdx.x * 256 + threadIdx.x;
  if (i < 628864){ uint4 z; z.x = z.y = z.z = z.w = 0u; xz[i] = z; return; }
  i -= 628864;
  if (i < 110592){
    int tap = i >> 12, co = (i >> 6) & 63, ci = i & 63;
    W4a[i] = __float2bfloat16(cr1w[(co * 64 + ci) * 27 + tap]); return;
  }
  i -= 110592;
  if (i < 110592){
    int tap = i >> 12, co = (i >> 6) & 63, ci = i & 63;
    W4b[i] = __float2bfloat16(cr2w[(co * 64 + ci) * 27 + tap]); return;
  }
  i -= 110592;
  if (i < 16384){
    int row = i >> 6, c = i & 63;
    float v = (row < 128) ? lw[row * 64 + c] : rwt[(row - 128) * 64 + c];
    Wlr[i] = __float2bfloat16(v); return;
  }
  i -= 16384;
  if (i < 20480){
    int row = i >> 7, k = i & 127;
    float v = (row < 128) ? dwt[row * 128 + k]
            : (row < 144 ? bw[(row - 128) * 128 + k] : cwp[(row - 144) * 128 + k]);
    Wd[i] = __float2bfloat16(v); return;
  }
  i -= 20480;
  if (i < 8192){ oWp[i] = __float2bfloat16(owt[i]); return; }
  i -= 8192;
  if (i < 16){ negA2[i] = -softplusf(alog[i]) * 1.44269504088896f; return; }
  i -= 16;
  if (i < 128){ uint4 z; z.x = z.y = z.z = z.w = 0u; statz[i] = z; return; }
}

// ---------------------------------------------------------------------------
// Pack fp32 NCDHW -> padded channels-last bf16 [b][h+1][w+1][d+1][c] (conv1).
// ---------------------------------------------------------------------------
__global__ __launch_bounds__(256) void pack_k(const float* __restrict__ xin,
                                              __hip_bfloat16* __restrict__ xpad)
{
  __shared__ float lds[64 * 33];
  const int t = threadIdx.x, blk = blockIdx.x;
  const int b = blk >> 10, h = (blk >> 5) & 31, w = blk & 31;
  const size_t rbase = ((size_t)(b * 64) << 15) + h * 1024 + w * 32;
  #pragma unroll
  for (int r = 0; r < 8; r++){
    int c = r * 8 + (t >> 5), d = t & 31;
    lds[c * 33 + d] = xin[rbase + (size_t)c * 32768 + d];
  }
  __syncthreads();
  const size_t wbase = (size_t)b * 2515456 + (size_t)(h + 1) * 73984 + (w + 1) * 2176 + 64;
  #pragma unroll
  for (int r = 0; r < 8; r++){
    int d = r * 4 + (t >> 6), c = t & 63;
    xpad[wbase + d * 64 + c] = __float2bfloat16(lds[c * 33 + d]);
  }
}

// ---------------------------------------------------------------------------
// Conv3d implicit GEMM, bf16 MFMA 16x16x32, LDS double-buffered (R26).
// ---------------------------------------------------------------------------
__global__ __launch_bounds__(256) void conv_mfma_k(const __hip_bfloat16* __restrict__ xpad,
    const __hip_bfloat16* __restrict__ W4, __hip_bfloat16* __restrict__ y,
    float* __restrict__ stats)
{
  __shared__ short smem[24576];  // 2 sets x 12288: per set B[0,8192) A[8192,12288)

  const int t = threadIdx.x;
  const int wave = t >> 6, lane = t & 63;
  const int quad = lane >> 4, ln = lane & 15;

  const int blk = blockIdx.x;          // 512 blocks
  const int xcd = blk & 7, j = blk >> 3;
  const int b = j >> 5, jj = j & 31;
  const int h = xcd * 4 + (jj >> 3);
  const int w0 = (jj & 7) * 4;

  const int bcol = (lane >> 2) * 64 + (lane & 3) * 8;
  const __hip_bfloat16* Bg = xpad + (size_t)b * 2515456 + (size_t)h * 73984
                                  + (size_t)(w0 + wave) * 2176 + bcol;
  const __hip_bfloat16* Ag = W4 + wave * 1024 + bcol;

  f32x4 acc[2][4];
  #pragma unroll
  for (int jn = 0; jn < 2; jn++)
    #pragma unroll
    for (int m = 0; m < 4; m++) acc[jn][m] = (f32x4){0.f, 0.f, 0.f, 0.f};

  const int aoff = ln * 32 + quad * 8;
  const int boffl = wave * 2048 + ln * 32 + quad * 8;

  // prologue: stage tap 0 into set 0
  {
    short* S = &smem[0];
    gld_lds16(Bg,              S + wave * 2048);
    gld_lds16(Bg + 1024,       S + wave * 2048 + 512);
    gld_lds16(Bg + 32,         S + wave * 2048 + 1024);
    gld_lds16(Bg + 1024 + 32,  S + wave * 2048 + 1536);
    gld_lds16(Ag,              S + 8192 + wave * 512);
    gld_lds16(Ag + 32,         S + 8192 + 2048 + wave * 512);
  }
  int cur = 0;
  for (int t1 = 0; t1 < 27; t1++){
    __syncthreads();   // drains vmcnt -> set[cur] ready; set[cur^1] free
    if (t1 + 1 < 27){
      const int t2 = t1 + 1;
      const int ki = t2 / 9, kj = (t2 / 3) % 3, kk = t2 % 3;
      const int tapoff = ki * 73984 + kj * 2176 + kk * 64;
      short* S = &smem[(cur ^ 1) * 12288];
      gld_lds16(Bg + tapoff,             S + wave * 2048);
      gld_lds16(Bg + tapoff + 1024,      S + wave * 2048 + 512);
      gld_lds16(Bg + tapoff + 32,        S + wave * 2048 + 1024);
      gld_lds16(Bg + tapoff + 1024 + 32, S + wave * 2048 + 1536);
      gld_lds16(Ag + t2 * 4096,          S + 8192 + wave * 512);
      gld_lds16(Ag + t2 * 4096 + 32,     S + 8192 + 2048 + wave * 512);
    }
    const int sb = cur * 12288;
    // channel-group 0 (ci 0-31)
    {
      short8 a0 = *(const short8*)&smem[sb + 8192 + aoff];
      short8 a1 = *(const short8*)&smem[sb + 8192 + 512 + aoff];
      short8 a2 = *(const short8*)&smem[sb + 8192 + 1024 + aoff];
      short8 a3 = *(const short8*)&smem[sb + 8192 + 1536 + aoff];
      short8 b0 = *(const short8*)&smem[sb + boffl];
      short8 b1 = *(const short8*)&smem[sb + boffl + 512];
      acc[0][0] = __builtin_amdgcn_mfma_f32_16x16x32_bf16(a0, b0, acc[0][0], 0, 0, 0);
      acc[0][1] = __builtin_amdgcn_mfma_f32_16x16x32_bf16(a1, b0, acc[0][1], 0, 0, 0);
      acc[0][2] = __builtin_amdgcn_mfma_f32_16x16x32_bf16(a2, b0, acc[0][2], 0, 0, 0);
      acc[0][3] = __builtin_amdgcn_mfma_f32_16x16x32_bf16(a3, b0, acc[0][3], 0, 0, 0);
      acc[1][0] = __builtin_amdgcn_mfma_f32_16x16x32_bf16(a0, b1, acc[1][0], 0, 0, 0);
      acc[1][1] = __builtin_amdgcn_mfma_f32_16x16x32_bf16(a1, b1, acc[1][1], 0, 0, 0);
      acc[1][2] = __builtin_amdgcn_mfma_f32_16x16x32_bf16(a2, b1, acc[1][2], 0, 0, 0);
      acc[1][3] = __builtin_amdgcn_mfma_f32_16x16x32_bf16(a3, b1, acc[1][3], 0, 0, 0);
    }
    // channel-group 1 (ci 32-63)
    {
      short8 a0 = *(const short8*)&smem[sb + 8192 + 2048 + aoff];
      short8 a1 = *(const short8*)&smem[sb + 8192 + 2048 + 512 + aoff];
      short8 a2 = *(const short8*)&smem[sb + 8192 + 2048 + 1024 + aoff];
      short8 a3 = *(const short8*)&smem[sb + 8192 + 2048 + 1536 + aoff];
      short8 b0 = *(const short8*)&smem[sb + boffl + 1024];
      short8 b1 = *(const short8*)&smem[sb + boffl + 1536];
      acc[0][0] = __builtin_amdgcn_mfma_f32_16x16x32_bf16(a0, b0, acc[0][0], 0, 0, 0);
      acc[0][1] = __builtin_amdgcn_mfma_f32_16x16x32_bf16(a1, b0, acc[0][1], 0, 0, 0);
      acc[0][2] = __builtin_amdgcn_mfma_f32_16x16x32_bf16(a2, b0, acc[0][2], 0, 0, 0);
      acc[0][3] = __builtin_amdgcn_mfma_f32_16x16x32_bf16(a3, b0, acc[0][3], 0, 0, 0);
      acc[1][0] = __builtin_amdgcn_mfma_f32_16x16x32_bf16(a0, b1, acc[1][0], 0, 0, 0);
      acc[1][1] = __builtin_amdgcn_mfma_f32_16x16x32_bf16(a1, b1, acc[1][1], 0, 0, 0);
      acc[1][2] = __builtin_amdgcn_mfma_f32_16x16x32_bf16(a2, b1, acc[1][2], 0, 0, 0);
      acc[1][3] = __builtin_amdgcn_mfma_f32_16x16x32_bf16(a3, b1, acc[1][3], 0, 0, 0);
    }
    cur ^= 1;
  }

  const size_t sbase = (size_t)h * 1024 + (w0 + wave) * 32 + ln;
  #pragma unroll
  for (int jn = 0; jn < 2; jn++){
    #pragma unroll
    for (int mt = 0; mt < 4; mt++){
      #pragma unroll
      for (int reg = 0; reg < 4; reg++){
        int co = mt * 16 + quad * 4 + reg;
        y[(((size_t)(b * 64 + co)) << 15) + sbase + jn * 16] = __float2bfloat16(acc[jn][mt][reg]);
      }
    }
  }

  // --- fused InstanceNorm partial stats: (sum, sumsq) per channel --------
  __syncthreads();                 // all smem reads done; reuse as float
  float* sred = (float*)smem;      // [wave][quad][mt][reg][2] = 512 floats
  #pragma unroll
  for (int mt = 0; mt < 4; mt++){
    #pragma unroll
    for (int reg = 0; reg < 4; reg++){
      float a0 = acc[0][mt][reg], a1 = acc[1][mt][reg];
      float s = a0 + a1, s2 = a0 * a0 + a1 * a1;
      #pragma unroll
      for (int m = 1; m < 16; m <<= 1){
        s  += __shfl_xor(s, m);
        s2 += __shfl_xor(s2, m);
      }
      if (ln == 0){
        const int idx = (((wave * 4 + quad) * 4 + mt) * 4 + reg) * 2;
        sred[idx] = s; sred[idx + 1] = s2;
      }
    }
  }
  __syncthreads();
  if (t < 128){
    const int k = t & 1, reg = (t >> 1) & 3, mt = (t >> 3) & 3, q = t >> 5;
    float v = 0.f;
    #pragma unroll
    for (int wv = 0; wv < 4; wv++)
      v += sred[(((wv * 4 + q) * 4 + mt) * 4 + reg) * 2 + k];
    const int co = mt * 16 + q * 4 + reg;
    atomicAdd(&stats[k * 128 + b * 64 + co], v);
  }
}

// ---------------------------------------------------------------------------
// Fused: InstanceNorm-apply + LeakyReLU + residual -> x1b (bf16 NCDHW)
// AND bf16 channels-last re-pack into xpad. mu/rs derived from (sum,sumsq).
// ---------------------------------------------------------------------------
__global__ __launch_bounds__(256) void apply_pack_k(const float* __restrict__ xin,
    const __hip_bfloat16* __restrict__ y, const float* __restrict__ stats,
    __hip_bfloat16* __restrict__ x1b, __hip_bfloat16* __restrict__ xpad)
{
  __shared__ float lds[64 * 33];
  const int t = threadIdx.x, blk = blockIdx.x;
  const int b = blk >> 10, h = (blk >> 5) & 31, w = blk & 31;
  const size_t rbase = ((size_t)(b * 64) << 15) + h * 1024 + w * 32;
  const int c = t >> 2, d0 = (t & 3) * 8;
  const float s1v = stats[b * 64 + c], s2v = stats[128 + b * 64 + c];
  const float mu = s1v * (1.0f / 32768.0f);
  const float var = s2v * (1.0f / 32768.0f) - mu * mu;
  const float rs = rsqrtf(fmaxf(var, 0.f) + 1e-5f);
  const size_t idx = rbase + (size_t)c * 32768 + d0;
  short8 yv = *(const short8*)&y[idx];
  float4 xa = *(const float4*)&xin[idx];
  float4 xb = *(const float4*)&xin[idx + 4];
  short8 o;
  #pragma unroll
  for (int jj = 0; jj < 8; jj++){
    float v = (b2f(yv[jj]) - mu) * rs;
    v = (v >= 0.0f) ? v : 0.01f * v;
    v += (jj < 4) ? ((const float*)&xa)[jj] : ((const float*)&xb)[jj - 4];
    o[jj] = f2b(v);
    lds[c * 33 + d0 + jj] = v;
  }
  *(short8*)&x1b[idx] = o;
  __syncthreads();
  const size_t wbase = (size_t)b * 2515456 + (size_t)(h + 1) * 73984 + (w + 1) * 2176 + 64;
  #pragma unroll
  for (int r = 0; r < 8; r++){
    int d = r * 4 + (t >> 6), cc = t & 63;
    xpad[wbase + d * 64 + cc] = __float2bfloat16(lds[cc * 33 + d]);
  }
}

// ---------------------------------------------------------------------------
// FUSED: InstanceNorm-apply + LeakyReLU + residual + LayerNorm over C
// + GEMM [64pos,64] x [64,256] -> Lbuf/Gbuf. lnx tile lives only in LDS.
// ---------------------------------------------------------------------------
__global__ __launch_bounds__(256) void ln_lr_k(const __hip_bfloat16* __restrict__ x1b,
    const __hip_bfloat16* __restrict__ y, const float* __restrict__ stats,
    const float* __restrict__ lnw, const float* __restrict__ lnb,
    const __hip_bfloat16* __restrict__ Wlr, __hip_bfloat16* __restrict__ Lb,
    __hip_bfloat16* __restrict__ Gb)
{
  __shared__ float lds_v[2][64 * 33];        // [w_loc][c*33+d]
  __shared__ float s_mu[64], s_rs[64];       // per pos_loc = w_loc*32+d
  __shared__ short s_ln[64 * 68];            // lnx tile bf16 [pos_loc][68]

  const int t = threadIdx.x, blk = blockIdx.x;   // 1024 blocks x 64 pos
  const int b = blk >> 9;
  const int h = (blk >> 4) & 31;
  const int w0 = (blk & 15) * 2;

  // Phase 1: IN-apply + leaky + residual for both w's -> lds_v (f32)
  const int c = t >> 2, d0 = (t & 3) * 8;
  const float s1v = stats[b * 64 + c], s2v = stats[128 + b * 64 + c];
  const float mu0 = s1v * (1.0f / 32768.0f);
  const float var0 = s2v * (1.0f / 32768.0f) - mu0 * mu0;
  const float rs0 = rsqrtf(fmaxf(var0, 0.f) + 1e-5f);
  #pragma unroll
  for (int wl = 0; wl < 2; wl++){
    const size_t rbase = ((size_t)(b * 64) << 15) + h * 1024 + (w0 + wl) * 32;
    const size_t idx = rbase + (size_t)c * 32768 + d0;
    short8 yv = *(const short8*)&y[idx];
    short8 xv = *(const short8*)&x1b[idx];
    #pragma unroll
    for (int jj = 0; jj < 8; jj++){
      float v = (b2f(yv[jj]) - mu0) * rs0;
      v = (v >= 0.0f) ? v : 0.01f * v;
      lds_v[wl][c * 33 + d0 + jj] = v + b2f(xv[jj]);
    }
  }
  __syncthreads();

  // Phase 2: LN stats per position (64 positions, over 64 channels)
  if (t < 64){
    const int wl = t >> 5, d = t & 31;
    float s = 0.f, s2 = 0.f;
    for (int cc = 0; cc < 64; cc++){
      float v = lds_v[wl][cc * 33 + d];
      s += v; s2 += v * v;
    }
    float mu = s * (1.f / 64.f);
    float var = s2 * (1.f / 64.f) - mu * mu;
    s_mu[t] = mu; s_rs[t] = rsqrtf(var + 1e-5f);
  }
  __syncthreads();

  // Phase 3: build bf16 lnx tile [pos_loc][68]
  {
    const int pos_loc = t >> 2, c0 = (t & 3) * 16;
    const int wl = pos_loc >> 5, d = pos_loc & 31;
    const float mu = s_mu[pos_loc], rs = s_rs[pos_loc];
    #pragma unroll
    for (int k = 0; k < 16; k++){
      const int cc = c0 + k;
      s_ln[pos_loc * 68 + cc] = f2b((lds_v[wl][cc * 33 + d] - mu) * rs * lnw[cc] + lnb[cc]);
    }
  }
  __syncthreads();

  // Phase 4: GEMM from LDS tile -> Lb (raw) / Gb (silu)
  const int wave = t >> 6, lane = t & 63, quad = lane >> 4, ln = lane & 15;
  const int pos0 = blk * 64 + wave * 16;
  f32x4 acc[16];
  #pragma unroll
  for (int nt = 0; nt < 16; nt++) acc[nt] = (f32x4){0.f, 0.f, 0.f, 0.f};
  #pragma unroll
  for (int ks = 0; ks < 2; ks++){
    short8 a = *(const short8*)&s_ln[(wave * 16 + ln) * 68 + ks * 32 + quad * 8];
    #pragma unroll
    for (int nt = 0; nt < 16; nt++){
      short8 bv = *(const short8*)&Wlr[(nt * 16 + ln) * 64 + ks * 32 + quad * 8];
      acc[nt] = __builtin_amdgcn_mfma_f32_16x16x32_bf16(a, bv, acc[nt], 0, 0, 0);
    }
  }
  #pragma unroll
  for (int nt = 0; nt < 16; nt++){
    int col = nt * 16 + ln;
    #pragma unroll
    for (int reg = 0; reg < 4; reg++){
      int pos = pos0 + quad * 4 + reg;
      float v = acc[nt][reg];
      if (col < 128) Lb[(size_t)pos * 128 + col] = __float2bfloat16(v);
      else           Gb[(size_t)pos * 128 + col - 128] = __float2bfloat16(siluf(v));
    }
  }
}

// ---------------------------------------------------------------------------
// FUSED per-axis: conv1d(k=4)+silu -> LDS | GEMM [64,128]x[128,160] -> LDS |
// selective scan (PACKED f32x2 math) + gate + post-LN + wax -> per-axis Y.
// ---------------------------------------------------------------------------
__global__ __launch_bounds__(256) void dbcscan_k(const __hip_bfloat16* __restrict__ Lb,
    const float* __restrict__ cw, const float* __restrict__ cb,
    const __hip_bfloat16* __restrict__ Wd, const float* __restrict__ db,
    const __hip_bfloat16* __restrict__ Gb, const float* __restrict__ negA2,
    const float* __restrict__ pnw, const float* __restrict__ pnb,
    const float* __restrict__ axw,
    __hip_bfloat16* __restrict__ Y0, __hip_bfloat16* __restrict__ Y1,
    __hip_bfloat16* __restrict__ Y2)
{
  __shared__ short s_xl[64 * 136];           // silu(conv1d) bf16, row = sl*32+l
  __shared__ short s_d[64 * 128];            // delta bf16; REUSED as gated-y
  __shared__ short s_Bh[2][32][16];          // B bf16 (R19 numerics)
  __shared__ short s_Ch[2][32][16];          // C bf16
  __shared__ float s_stat[2][32][2];         // per-l {sum, sumsq}

  const int t = threadIdx.x;
  const int bid = blockIdx.x;
  const int axis = bid % 3;                  // interleave axes across dispatch
  const int j = bid / 3;                     // 0..1023 (seq pair)
  int sigma;
  if (axis == 0)      sigma = 1024;
  else if (axis == 1) sigma = 32;
  else                sigma = 1;
  __hip_bfloat16* Yax = (axis == 0) ? Y0 : (axis == 1) ? Y1 : Y2;

  // bases for this block's two sequences
  int bases[2];
  #pragma unroll
  for (int s = 0; s < 2; s++){
    const int seq = j * 2 + s;
    const int b = seq >> 10, r1 = (seq >> 5) & 31, r0 = seq & 31;
    if (axis == 0)      bases[s] = b * 32768 + r1 * 32 + r0;
    else if (axis == 1) bases[s] = b * 32768 + r1 * 1024 + r0;
    else                bases[s] = b * 32768 + r1 * 1024 + r0 * 32;
  }

  // --- Phase A: conv1d(k=4) + silu -> s_xl --------------------------------
  {
    const int c0 = (t & 15) * 8;
    const int pibase = t >> 4;
    float4 w4[8]; float cbv[8];
    #pragma unroll
    for (int c = 0; c < 8; c++){ w4[c] = *(const float4*)&cw[(c0 + c) * 4]; cbv[c] = cb[c0 + c]; }
    #pragma unroll
    for (int r = 0; r < 4; r++){
      const int row = pibase + r * 16;          // 0..63
      const int sl_ = row >> 5, l = row & 31;
      const int pos = bases[sl_] + l * sigma;
      float acc[8];
      #pragma unroll
      for (int c = 0; c < 8; c++) acc[c] = cbv[c];
      #pragma unroll
      for (int jt = 0; jt < 4; jt++){
        const int off = 3 - jt;
        if (l >= off){
          short8 lv = *(const short8*)&Lb[(size_t)(pos - off * sigma) * 128 + c0];
          #pragma unroll
          for (int c = 0; c < 8; c++){
            float wv = (jt == 0) ? w4[c].x : (jt == 1) ? w4[c].y : (jt == 2) ? w4[c].z : w4[c].w;
            acc[c] += wv * b2f(lv[c]);
          }
        }
      }
      short8 o;
      #pragma unroll
      for (int c = 0; c < 8; c++) o[c] = f2b(siluf(acc[c]));
      *(short8*)&s_xl[row * 136 + c0] = o;
    }
  }
  __syncthreads();

  // --- Phase B: GEMM [64,128] x [128,160]; epilogue -> s_d / s_Bh / s_Ch --
  const int wave = t >> 6, lane = t & 63, quad = lane >> 4, ln = lane & 15;
  {
    const int rowb = (wave * 16 + ln) * 136;
    f32x4 acc2[10];
    #pragma unroll
    for (int nt = 0; nt < 10; nt++) acc2[nt] = (f32x4){0.f, 0.f, 0.f, 0.f};
    #pragma unroll
    for (int ks = 0; ks < 4; ks++){
      short8 a = *(const short8*)&s_xl[rowb + ks * 32 + quad * 8];
      #pragma unroll
      for (int nt = 0; nt < 10; nt++){
        short8 bv = *(const short8*)&Wd[(nt * 16 + ln) * 128 + ks * 32 + quad * 8];
        acc2[nt] = __builtin_amdgcn_mfma_f32_16x16x32_bf16(a, bv, acc2[nt], 0, 0, 0);
      }
    }
    const int row0 = wave * 16 + quad * 4;
    #pragma unroll
    for (int nt = 0; nt < 10; nt++){
      const int col = nt * 16 + ln;
      const bool isd = col < 128;
      const float dbv = isd ? db[col] : 0.f;
      #pragma unroll
      for (int reg = 0; reg < 4; reg++){
        const int row = row0 + reg;
        float v = acc2[nt][reg];
        if (isd){
          v = fminf(fmaxf(softplus_hw(v + dbv), 1e-4f), 10.f);
          s_d[row * 128 + col] = f2b(v);
        } else {
          const int sl_ = row >> 5, l = row & 31, cc = col - 128;
          if (cc < 16) s_Bh[sl_][l][cc] = f2b(v);
          else         s_Ch[sl_][l][cc - 16] = f2b(v);
        }
      }
    }
  }

  // scan setup: packed state pairs
  f32x2 A22[8], h2[8];
  #pragma unroll
  for (int s = 0; s < 8; s++){
    A22[s] = (f32x2){negA2[2 * s], negA2[2 * s + 1]};
    h2[s] = (f32x2){0.f, 0.f};
  }
  const int sl = wave >> 1;                  // seq_local 0/1
  const int half = wave & 1;                 // channel half 0/1
  const int ch = half * 64 + lane;
  const int base = bases[sl];
  const size_t sx = (size_t)sigma * 128;
  const __hip_bfloat16* pg = Gb + (size_t)base * 128 + ch;

  __syncthreads();

  // --- Phase C1: serial scan (f32x2 packed); dt/xt/B/C from LDS ----------
  unsigned short gu = *(const unsigned short*)pg;
  #pragma unroll
  for (int l = 0; l < 32; l++){
    unsigned short ngu = 0;
    if (l + 1 < 32) ngu = *(const unsigned short*)(pg + sx);
    const int row = sl * 32 + l;
    float dt = b2f(s_d[row * 128 + ch]);
    float xt = b2f(s_xl[row * 136 + ch]);
    float g = b2f((short)gu);
    float dx = dt * xt;
    const f32x2 dt2 = (f32x2){dt, dt};
    const f32x2 dx2 = (f32x2){dx, dx};
    // B/C as packed u32 (2 bf16 each): 8 pairs per operand
    uint4 Bu0 = *(const uint4*)&s_Bh[sl][l][0];
    uint4 Bu1 = *(const uint4*)&s_Bh[sl][l][8];
    uint4 Cu0 = *(const uint4*)&s_Ch[sl][l][0];
    uint4 Cu1 = *(const uint4*)&s_Ch[sl][l][8];
    const unsigned int Bw[8] = {Bu0.x, Bu0.y, Bu0.z, Bu0.w, Bu1.x, Bu1.y, Bu1.z, Bu1.w};
    const unsigned int Cw[8] = {Cu0.x, Cu0.y, Cu0.z, Cu0.w, Cu1.x, Cu1.y, Cu1.z, Cu1.w};
    f32x2 y2 = (f32x2){0.f, 0.f};
    #pragma unroll
    for (int i = 0; i < 8; i++){
      f32x2 dtA = dt2 * A22[i];                       // v_pk_mul_f32
      f32x2 es = (f32x2){__builtin_amdgcn_exp2f(dtA.x),
                         __builtin_amdgcn_exp2f(dtA.y)};
      h2[i] = es * h2[i] + dx2 * bf2x(Bw[i]);         // 2x v_pk ops
      y2 = y2 + h2[i] * bf2x(Cw[i]);                  // v_pk_fma_f32
    }
    float y = y2.x + y2.y;
    s_d[row * 128 + ch] = f2b(y * g);        // alias write (gated y)
    gu = ngu;
    pg += sx;
  }
  __syncthreads();

  // --- Phase C2: cooperative per-l reduction (sum, sumsq over 128 ch) ----
  {
    const int row = t >> 2, part = t & 3;    // row = sl2*32 + l2
    const int sl2 = row >> 5, l2 = row & 31;
    const short* yr = &s_d[row * 128 + part * 32];
    float s1 = 0.f, s2 = 0.f;
    #pragma unroll
    for (int i = 0; i < 32; i++){
      float v = b2f(yr[i]);
      s1 += v; s2 += v * v;
    }
    s1 += __shfl_xor(s1, 1); s2 += __shfl_xor(s2, 1);
    s1 += __shfl_xor(s1, 2); s2 += __shfl_xor(s2, 2);
    if (part == 0){ s_stat[sl2][l2][0] = s1; s_stat[sl2][l2][1] = s2; }
  }
  __syncthreads();

  // --- Phase C3: LN over 128 ch + wax -> per-axis Y (store, no RMW) ------
  float a0 = axw[0], a1 = axw[1], a2 = axw[2];
  float mxw = fmaxf(a0, fmaxf(a1, a2));
  float e0 = __expf(a0 - mxw), e1 = __expf(a1 - mxw), e2 = __expf(a2 - mxw);
  float wax = ((axis == 0) ? e0 : (axis == 1) ? e1 : e2) / (e0 + e1 + e2);
  const float pw = pnw[ch], pb = pnb[ch];

  __hip_bfloat16* py = Yax + (size_t)base * 128 + ch;
  #pragma unroll
  for (int l = 0; l < 32; l++){
    float ss1 = s_stat[sl][l][0];
    float ss2 = s_stat[sl][l][1];
    float mu = ss1 * (1.f / 128.f);
    float var = ss2 * (1.f / 128.f) - mu * mu;
    float rs = rsqrtf(fmaxf(var, 0.f) + 1e-5f);
    float yv = b2f(s_d[(sl * 32 + l) * 128 + ch]);
    float o = ((yv - mu) * rs * pw + pb) * wax;
    *(unsigned short*)py = (unsigned short)f2b(o);
    py += sx;
  }
}

// ---------------------------------------------------------------------------
// SINGLE out-projection GEMM over Y0+Y1+Y2 (MFMA is linear in B: three
// accumulating MFMAs sum the axes exactly) + residual finalize.
// ---------------------------------------------------------------------------
__global__ __launch_bounds__(256) void gemm_out_k(const __hip_bfloat16* __restrict__ Y0,
    const __hip_bfloat16* __restrict__ Y1, const __hip_bfloat16* __restrict__ Y2,
    const __hip_bfloat16* __restrict__ oW, const float* __restrict__ xres,
    const float* __restrict__ rsc, float* __restrict__ outp)
{
  const int t = threadIdx.x, wave = t >> 6, lane = t & 63, quad = lane >> 4, ln = lane & 15;
  const int pos0 = blockIdx.x * 64 + wave * 16;
  f32x4 acc[4];
  #pragma unroll
  for (int mt = 0; mt < 4; mt++) acc[mt] = (f32x4){0.f, 0.f, 0.f, 0.f};
  #pragma unroll
  for (int ks = 0; ks < 4; ks++){
    const size_t boffs = (size_t)(pos0 + ln) * 128 + ks * 32 + quad * 8;
    short8 bv0 = *(const short8*)&Y0[boffs];
    short8 bv1 = *(const short8*)&Y1[boffs];
    short8 bv2 = *(const short8*)&Y2[boffs];
    #pragma unroll
    for (int mt = 0; mt < 4; mt++){
      short8 a = *(const short8*)&oW[(mt * 16 + ln) * 128 + ks * 32 + quad * 8];
      acc[mt] = __builtin_amdgcn_mfma_f32_16x16x32_bf16(a, bv0, acc[mt], 0, 0, 0);
      acc[mt] = __builtin_amdgcn_mfma_f32_16x16x32_bf16(a, bv1, acc[mt], 0, 0, 0);
      acc[mt] = __builtin_amdgcn_mfma_f32_16x16x32_bf16(a, bv2, acc[mt], 0, 0, 0);
    }
  }
  float rs = rsc[0];
  const int pos = pos0 + ln;
  const int bb = pos >> 15, hwd = pos & 32767;
  #pragma unroll
  for (int mt = 0; mt < 4; mt++){
    #pragma unroll
    for (int reg = 0; reg < 4; reg++){
      int co = mt * 16 + quad * 4 + reg;
      size_t idx = (((size_t)(bb * 64 + co)) << 15) + hwd;
      outp[idx] = xres[idx] + rs * acc[mt][reg];
    }
  }
}

// ---------------------------------------------------------------------------
extern "C" void kernel_launch(void* const* d_in, const int* in_sizes, int n_in,
                              void* d_out, int out_size, void* d_ws, size_t ws_size,
                              hipStream_t stream)
{
  const float* x      = (const float*)d_in[0];
  const float* cr1w   = (const float*)d_in[1];
  const float* cr2w   = (const float*)d_in[3];
  const float* ln_w   = (const float*)d_in[5];
  const float* ln_b   = (const float*)d_in[6];
  const float* left_w = (const float*)d_in[7];
  const float* c1dw   = (const float*)d_in[8];
  const float* c1db   = (const float*)d_in[9];
  const float* dw     = (const float*)d_in[10];
  const float* db     = (const float*)d_in[11];
  const float* bpw    = (const float*)d_in[12];
  const float* cpw    = (const float*)d_in[13];
  const float* alog   = (const float*)d_in[14];
  const float* rw     = (const float*)d_in[15];
  const float* pnw    = (const float*)d_in[16];
  const float* pnb    = (const float*)d_in[17];
  const float* ow     = (const float*)d_in[18];
  const float* rsc    = (const float*)d_in[19];
  const float* axw    = (const float*)d_in[20];
  float* out = (float*)d_out;                       // final out; ybuf alias pre-gemm_out
  float* wsf = (float*)d_ws;

  __hip_bfloat16* ybuf = (__hip_bfloat16*)d_out;               // conv out bf16 (33.5MB < 67MB)
  __hip_bfloat16* x1b  = (__hip_bfloat16*)wsf;                 // x1 bf16 (dead after ln_lr -> Y0)
  float* stats1 = wsf + 4194304;                               // 256 f (sum | sumsq)
  float* stats2 = wsf + 4194560;                               // 256 f
  float* negA2  = wsf + 4194816;                               // 16 f
  __hip_bfloat16* W4a  = (__hip_bfloat16*)(wsf + 4195072);     // 110,592 bf16
  __hip_bfloat16* W4b  = W4a + 110592;                         // ends f-off 4,305,664
  __hip_bfloat16* Wlr  = (__hip_bfloat16*)(wsf + 4305664);     // 16,384 bf16
  __hip_bfloat16* Wdbc = (__hip_bfloat16*)(wsf + 4313856);     // 20,480 bf16
  __hip_bfloat16* oWp  = (__hip_bfloat16*)(wsf + 4324096);     // 8,192 bf16
  __hip_bfloat16* xpad = (__hip_bfloat16*)(wsf + 4328192);     // 5,030,912 bf16
  __hip_bfloat16* Lbuf = (__hip_bfloat16*)(wsf + 6843648);     // 8,388,608 bf16
  __hip_bfloat16* Gbuf = (__hip_bfloat16*)(wsf + 11037952);    // 8,388,608 bf16
  __hip_bfloat16* Y0   = (__hip_bfloat16*)wsf;                 // (x1b region, post-ln_lr)
  __hip_bfloat16* Y1   = (__hip_bfloat16*)(wsf + 15232256);    // 8,388,608 bf16
  __hip_bfloat16* Y2   = (__hip_bfloat16*)(wsf + 19426560);    // 8,388,608 bf16

  setup_k<<<3498, 256, 0, stream>>>((uint4*)xpad, cr1w, cr2w, left_w, rw, dw, bpw, cpw, ow,
                                    alog, W4a, W4b, Wlr, Wdbc, oWp, negA2,
                                    (uint4*)stats1);

  // conv-res block 1 (stats fused into conv epilogue)
  pack_k<<<2048, 256, 0, stream>>>(x, xpad);
  conv_mfma_k<<<512, 256, 0, stream>>>(xpad, W4a, ybuf, stats1);
  apply_pack_k<<<2048, 256, 0, stream>>>(x, ybuf, stats1, x1b, xpad);
  // conv-res block 2 + fused LN + left/right projection (lnx never in HBM)
  conv_mfma_k<<<512, 256, 0, stream>>>(xpad, W4b, ybuf, stats2);
  ln_lr_k<<<1024, 256, 0, stream>>>(x1b, ybuf, stats2, ln_w, ln_b, Wlr, Lbuf, Gbuf);

  // ALL 3 axes in one launch (axis = bid%3); per-axis Y buffers, no RMW
  dbcscan_k<<<3072, 256, 0, stream>>>(Lbuf, c1dw, c1db, Wdbc, db, Gbuf, negA2,
                                      pnw, pnb, axw, Y0, Y1, Y2);

  // single out-projection over Y0+Y1+Y2 + residual finalize
  gemm_out_k<<<1024, 256, 0, stream>>>(Y0, Y1, Y2, oWp, x, rsc, out);
}